// Round 1
// baseline (891.327 us; speedup 1.0000x reference)
//
#include <hip/hip_runtime.h>
#include <math.h>

#define T_LEN   2048
#define B_ROWS  4096
#define F_IN    16
#define HID     32
#define NCH     12
#define L_OUT   1023
#define CHUNK   16
#define NCHUNK  (T_LEN / CHUNK)

__device__ __forceinline__ float dot4(const float4 v, const float* __restrict__ w, float acc) {
    acc = fmaf(v.x, w[0], acc);
    acc = fmaf(v.y, w[1], acc);
    acc = fmaf(v.z, w[2], acc);
    acc = fmaf(v.w, w[3], acc);
    return acc;
}

// One wave = 2 rows (32 lanes/row, lane j owns hidden unit j). All h/act
// exchange is intra-wave through LDS -> no __syncthreads anywhere.
__global__ __launch_bounds__(256, 2)
void rnn_pool_kernel(const float* __restrict__ x,
                     const float* __restrict__ W_ih,
                     const float* __restrict__ W_hh,
                     const float* __restrict__ b_ih,
                     const float* __restrict__ b_hh,
                     const float* __restrict__ W_proj,
                     const float* __restrict__ b_proj,
                     float* __restrict__ out)
{
    __shared__ alignas(16) float xbuf[4][2][CHUNK][F_IN];  // [wave][row][t][f] 16KB
    __shared__ alignas(16) float hbuf[8][HID];             // pre-activation h
    __shared__ alignas(16) float abuf[8][HID];             // RReLU(h)

    const int tid  = threadIdx.x;
    const int wid  = tid >> 6;
    const int lane = tid & 63;
    const int sub  = lane >> 5;        // which of the wave's 2 rows
    const int l32  = lane & 31;
    const int rowl = (wid << 1) + sub; // row slot within block (0..7)
    const int rowBase = blockIdx.x * 8 + (wid << 1);
    const int row  = rowBase + sub;

    // ---- resident per-lane weights ----
    const int j = l32;                 // hidden unit owned by this lane
    float wih[F_IN];
    #pragma unroll
    for (int m = 0; m < 4; ++m) {
        float4 v = ((const float4*)(W_ih + j * F_IN))[m];
        wih[4*m+0]=v.x; wih[4*m+1]=v.y; wih[4*m+2]=v.z; wih[4*m+3]=v.w;
    }
    float whh[HID];
    #pragma unroll
    for (int m = 0; m < 8; ++m) {
        float4 v = ((const float4*)(W_hh + j * HID))[m];
        whh[4*m+0]=v.x; whh[4*m+1]=v.y; whh[4*m+2]=v.z; whh[4*m+3]=v.w;
    }
    const float bias = b_ih[j] + b_hh[j];

    // projection: lanes 0..23 = (channel, half); half-dot of 16 elements
    const int craw = l32 >> 1;
    const int cc   = craw < NCH ? craw : NCH - 1;   // clamp for lanes 24..31
    const int halfk = l32 & 1;
    float wp[16];
    #pragma unroll
    for (int m = 0; m < 4; ++m) {
        float4 v = ((const float4*)(W_proj + cc * HID + halfk * 16))[m];
        wp[4*m+0]=v.x; wp[4*m+1]=v.y; wp[4*m+2]=v.z; wp[4*m+3]=v.w;
    }
    const float bpc = b_proj[cc];
    const bool pool_lane = (l32 < 24) && ((l32 & 1) == 0);

    // ---- init ----
    hbuf[rowl][j] = 0.0f;
    abuf[rowl][j] = 0.0f;

    const float4* xsrc0 = (const float4*)(x + (size_t)(rowBase + 0) * T_LEN * F_IN);
    const float4* xsrc1 = (const float4*)(x + (size_t)(rowBase + 1) * T_LEN * F_IN);
    float4* xw0 = (float4*)(&xbuf[wid][0][0][0]);   // 64 float4 = one row-chunk
    float4* xw1 = (float4*)(&xbuf[wid][1][0][0]);

    // prefetch chunk 0 into registers
    float4 xs0 = xsrc0[lane];
    float4 xs1 = xsrc1[lane];

    float Wcur = 0.0f;                 // rolling LP-pool window accumulator
    float* outrow = out + (size_t)row * L_OUT;

    for (int ch = 0; ch < NCHUNK; ++ch) {
        // commit staged chunk to LDS (DS FIFO orders vs. prior chunk's reads)
        xw0[lane] = xs0;
        xw1[lane] = xs1;
        // prefetch next chunk (clamped on the last -> uniform control flow)
        const int chn = (ch + 1 < NCHUNK) ? (ch + 1) : (NCHUNK - 1);
        xs0 = xsrc0[chn * 64 + lane];
        xs1 = xsrc1[chn * 64 + lane];

        #pragma unroll
        for (int tt = 0; tt < CHUNK; ++tt) {
            const int t = (ch << 4) + tt;

            // issue all LDS reads up front
            const float4* xp = (const float4*)(&xbuf[wid][sub][tt][0]);
            const float4 xv0 = xp[0], xv1 = xp[1], xv2 = xp[2], xv3 = xp[3];
            const float4* hp = (const float4*)(&hbuf[rowl][0]);      // h_{t-1}
            const float4 h0 = hp[0], h1 = hp[1], h2 = hp[2], h3 = hp[3];
            const float4 h4 = hp[4], h5 = hp[5], h6 = hp[6], h7 = hp[7];
            const float4* ap = (const float4*)(&abuf[rowl][halfk << 4]); // act(h_{t-1})
            const float4 a0 = ap[0], a1 = ap[1], a2 = ap[2], a3 = ap[3];

            // z_j = x_t . W_ih[j] + h_{t-1} . W_hh[j] + bias  (4 indep chains)
            float acc0 = bias, acc1 = 0.f, acc2 = 0.f, acc3 = 0.f;
            acc0 = dot4(xv0, wih + 0,  acc0);
            acc1 = dot4(xv1, wih + 4,  acc1);
            acc2 = dot4(xv2, wih + 8,  acc2);
            acc3 = dot4(xv3, wih + 12, acc3);
            acc0 = dot4(h0, whh + 0,  acc0);
            acc1 = dot4(h1, whh + 4,  acc1);
            acc2 = dot4(h2, whh + 8,  acc2);
            acc3 = dot4(h3, whh + 12, acc3);
            acc0 = dot4(h4, whh + 16, acc0);
            acc1 = dot4(h5, whh + 20, acc1);
            acc2 = dot4(h6, whh + 24, acc2);
            acc3 = dot4(h7, whh + 28, acc3);

            // ---- projection + pooling for step t-1 (deferred one step) ----
            if (t > 0) {
                float pa0 = 0.f, pa1 = 0.f;
                pa0 = dot4(a0, wp + 0,  pa0);
                pa1 = dot4(a1, wp + 4,  pa1);
                pa0 = dot4(a2, wp + 8,  pa0);
                pa1 = dot4(a3, wp + 12, pa1);
                float pa = pa0 + pa1;
                float pb = __shfl_xor(pa, 1, 32);   // combine the two halves
                float p  = pa + pb + bpc;           // valid on even lanes < 24
                float q  = p * p;
                const int tq = t - 1;
                if ((tq & 1) == 0) {
                    const float prev = Wcur + q;    // closes window tq/2 - 1
                    if (tq >= 2) {
                        float v = pool_lane ? prev : 0.0f;  // q >= 0, so 0-pad is safe
                        v = fmaxf(v, __shfl_xor(v, 16, 32));
                        v = fmaxf(v, __shfl_xor(v, 8, 32));
                        v = fmaxf(v, __shfl_xor(v, 4, 32));
                        v = fmaxf(v, __shfl_xor(v, 2, 32));
                        v = fmaxf(v, __shfl_xor(v, 1, 32));
                        if (l32 == 0) outrow[(tq >> 1) - 1] = __builtin_amdgcn_sqrtf(v);
                    }
                    Wcur = q;                       // opens window tq/2
                } else {
                    Wcur += q;
                }
            }

            // tanh(z) = 1 - 2/(exp2(z*2log2e) + 1)
            const float z  = (acc0 + acc1) + (acc2 + acc3);
            const float e  = __builtin_amdgcn_exp2f(z * 2.8853900817779268f);
            const float r  = __builtin_amdgcn_rcpf(e + 1.0f);
            const float hn = fmaf(-2.0f, r, 1.0f);
            const float an = fmaf(0.229f, fminf(hn, 0.0f), fmaxf(hn, 0.0f)); // eval RReLU
            hbuf[rowl][j] = hn;   // writes after all reads of this iter; DS FIFO
            abuf[rowl][j] = an;   // orders them vs. next iter's reads
        }
    }
}

extern "C" void kernel_launch(void* const* d_in, const int* in_sizes, int n_in,
                              void* d_out, int out_size, void* d_ws, size_t ws_size,
                              hipStream_t stream) {
    const float* x      = (const float*)d_in[0];
    const float* W_ih   = (const float*)d_in[1];
    const float* W_hh   = (const float*)d_in[2];
    const float* b_ih   = (const float*)d_in[3];
    const float* b_hh   = (const float*)d_in[4];
    const float* W_proj = (const float*)d_in[5];
    const float* b_proj = (const float*)d_in[6];
    float* out = (float*)d_out;

    dim3 grid(B_ROWS / 8);   // 512 blocks * 4 waves = 2048 waves = 2/SIMD
    dim3 block(256);
    hipLaunchKernelGGL(rnn_pool_kernel, grid, block, 0, stream,
                       x, W_ih, W_hh, b_ih, b_hh, W_proj, b_proj, out);
}

// Round 2
// 885.043 us; speedup vs baseline: 1.0071x; 1.0071x over previous
//
#include <hip/hip_runtime.h>
#include <math.h>

#define T_LEN   2048
#define B_ROWS  4096
#define F_IN    16
#define HID     32
#define NCH     12
#define L_OUT   1023
#define CHUNK   16
#define NCHUNK  (T_LEN / CHUNK)
#define RRELU_SLOPE 0.229f

typedef _Float16 h2 __attribute__((ext_vector_type(2)));

__device__ __forceinline__ h2 mk2(float a, float b) {
    h2 r; r.x = (_Float16)a; r.y = (_Float16)b; return r;
}
__device__ __forceinline__ h2 as_h2(unsigned u) { return __builtin_bit_cast(h2, u); }
__device__ __forceinline__ unsigned pk2(float a, float b) {
    return __builtin_bit_cast(unsigned, mk2(a, b));
}

__device__ __forceinline__ float fdot2(h2 a, h2 b, float c) {
#if __has_builtin(__builtin_amdgcn_fdot2)
    return __builtin_amdgcn_fdot2(a, b, c, false);
#else
    float r;
    asm("v_dot2_f32_f16 %0, %1, %2, %3" : "=v"(r) : "v"(a), "v"(b), "v"(c));
    return r;
#endif
}

#define QP_XOR1 0xB1   // quad_perm [1,0,3,2]
template<int CTRL>
__device__ __forceinline__ unsigned dppu(unsigned v) {
    return (unsigned)__builtin_amdgcn_mov_dpp((int)v, CTRL, 0xF, 0xF, false);
}
__device__ __forceinline__ uint4 dpp_xor1_u4(uint4 v) {
    uint4 r;
    r.x = dppu<QP_XOR1>(v.x); r.y = dppu<QP_XOR1>(v.y);
    r.z = dppu<QP_XOR1>(v.z); r.w = dppu<QP_XOR1>(v.w);
    return r;
}
__device__ __forceinline__ float dpp_xor1_f(float v) {
    return __uint_as_float(dppu<QP_XOR1>(__float_as_uint(v)));
}

// One wave = 2 rows (32 lanes/row, lane j owns hidden unit j). All exchange is
// intra-wave (LDS fp16 broadcast + DPP pair-exchange) -> no __syncthreads.
__global__ __launch_bounds__(256, 2)
void rnn_pool_kernel(const float* __restrict__ x,
                     const float* __restrict__ W_ih,
                     const float* __restrict__ W_hh,
                     const float* __restrict__ b_ih,
                     const float* __restrict__ b_hh,
                     const float* __restrict__ W_proj,
                     const float* __restrict__ b_proj,
                     float* __restrict__ out)
{
    __shared__ alignas(16) _Float16 xbuf[4][2][CHUNK][F_IN];  // 4 KB
    __shared__ alignas(16) _Float16 hbuf[8][HID];             // 512 B

    const int tid  = threadIdx.x;
    const int wid  = tid >> 6;
    const int lane = tid & 63;
    const int sub  = lane >> 5;        // which of the wave's 2 rows
    const int l32  = lane & 31;
    const int par  = l32 & 1;          // parity: which half of K this lane reads
    const int rowl = (wid << 1) + sub; // row slot within block (0..7)
    const int rowBase = blockIdx.x * 8 + (wid << 1);
    const int row  = rowBase + sub;

    // ---- resident per-lane weights (fp16 pairs, parity-ordered) ----
    const int j = l32;                 // hidden unit owned by this lane
    h2 whh2[16];
    #pragma unroll
    for (int half = 0; half < 2; ++half) {
        const int kb = (half ? (1 - par) : par) * 16;  // own range first, partner second
        #pragma unroll
        for (int i = 0; i < 8; ++i)
            whh2[half * 8 + i] = mk2(W_hh[j * HID + kb + 2 * i],
                                     W_hh[j * HID + kb + 2 * i + 1]);
    }
    h2 wih2[8];
    #pragma unroll
    for (int half = 0; half < 2; ++half) {
        const int kb = (half ? (1 - par) : par) * 8;
        #pragma unroll
        for (int i = 0; i < 4; ++i)
            wih2[half * 4 + i] = mk2(W_ih[j * F_IN + kb + 2 * i],
                                     W_ih[j * F_IN + kb + 2 * i + 1]);
    }
    const float bias = b_ih[j] + b_hh[j];

    // projection: lane pair (c = l32>>1, halfk = par); halfk half == own h read
    const int craw = l32 >> 1;
    const int cc   = craw < NCH ? craw : NCH - 1;   // clamp for lanes 24..31
    h2 wp2[8];
    #pragma unroll
    for (int i = 0; i < 8; ++i)
        wp2[i] = mk2(W_proj[cc * HID + par * 16 + 2 * i],
                     W_proj[cc * HID + par * 16 + 2 * i + 1]);
    const float bpc = b_proj[cc];
    const bool pool_lane = (l32 < 24) && (par == 0);
    const h2 sl2 = mk2(RRELU_SLOPE, RRELU_SLOPE);

    // ---- init ----
    hbuf[rowl][j] = (_Float16)0.0f;

    const float4* xsrc0 = (const float4*)(x + (size_t)(rowBase + 0) * T_LEN * F_IN);
    const float4* xsrc1 = (const float4*)(x + (size_t)(rowBase + 1) * T_LEN * F_IN);
    uint2* xw0 = (uint2*)(&xbuf[wid][0][0][0]);   // 64 x 8B = one fp16 row-chunk
    uint2* xw1 = (uint2*)(&xbuf[wid][1][0][0]);

    // prefetch chunk 0 into registers (fp32)
    float4 xs0 = xsrc0[lane];
    float4 xs1 = xsrc1[lane];

    const _Float16* hrd = &hbuf[rowl][par * 16];        // own-parity 16 halves
    const _Float16* xrd = &xbuf[wid][sub][0][par * 8];  // own-parity 8 halves

    float Wcur = 0.0f;                 // rolling LP-pool window accumulator
    float* outrow = out + (size_t)row * L_OUT;

    for (int ch = 0; ch < NCHUNK; ++ch) {
        // convert + commit staged chunk to LDS (per-wave DS FIFO ordering)
        xw0[lane] = make_uint2(pk2(xs0.x, xs0.y), pk2(xs0.z, xs0.w));
        xw1[lane] = make_uint2(pk2(xs1.x, xs1.y), pk2(xs1.z, xs1.w));
        // prefetch next chunk (clamped on the last -> uniform control flow)
        const int chn = (ch + 1 < NCHUNK) ? (ch + 1) : (NCHUNK - 1);
        xs0 = xsrc0[chn * 64 + lane];
        xs1 = xsrc1[chn * 64 + lane];

        #pragma unroll
        for (int tt = 0; tt < CHUNK; ++tt) {
            const int t = (ch << 4) + tt;

            // own-parity LDS reads (3 x b128 per lane)
            const uint4* hp = (const uint4*)hrd;
            const uint4 hA0 = hp[0];
            const uint4 hA1 = hp[1];
            const uint4* xp = (const uint4*)(xrd + tt * F_IN);
            const uint4 xA  = xp[0];

            // partner halves via DPP quad-perm (pure VALU, no LDS pipe)
            const uint4 hB0 = dpp_xor1_u4(hA0);
            const uint4 hB1 = dpp_xor1_u4(hA1);
            const uint4 xB  = dpp_xor1_u4(xA);

            // z_j = x_t . W_ih[j] + h_{t-1} . W_hh[j] + bias  (4 indep chains)
            float a0 = bias, a1 = 0.f, a2 = 0.f, a3 = 0.f;
            a0 = fdot2(as_h2(xA.x), wih2[0], a0);
            a1 = fdot2(as_h2(xA.y), wih2[1], a1);
            a2 = fdot2(as_h2(xA.z), wih2[2], a2);
            a3 = fdot2(as_h2(xA.w), wih2[3], a3);
            a0 = fdot2(as_h2(xB.x), wih2[4], a0);
            a1 = fdot2(as_h2(xB.y), wih2[5], a1);
            a2 = fdot2(as_h2(xB.z), wih2[6], a2);
            a3 = fdot2(as_h2(xB.w), wih2[7], a3);

            a0 = fdot2(as_h2(hA0.x), whh2[0],  a0);
            a1 = fdot2(as_h2(hA0.y), whh2[1],  a1);
            a2 = fdot2(as_h2(hA0.z), whh2[2],  a2);
            a3 = fdot2(as_h2(hA0.w), whh2[3],  a3);
            a0 = fdot2(as_h2(hA1.x), whh2[4],  a0);
            a1 = fdot2(as_h2(hA1.y), whh2[5],  a1);
            a2 = fdot2(as_h2(hA1.z), whh2[6],  a2);
            a3 = fdot2(as_h2(hA1.w), whh2[7],  a3);
            a0 = fdot2(as_h2(hB0.x), whh2[8],  a0);
            a1 = fdot2(as_h2(hB0.y), whh2[9],  a1);
            a2 = fdot2(as_h2(hB0.z), whh2[10], a2);
            a3 = fdot2(as_h2(hB0.w), whh2[11], a3);
            a0 = fdot2(as_h2(hB1.x), whh2[12], a0);
            a1 = fdot2(as_h2(hB1.y), whh2[13], a1);
            a2 = fdot2(as_h2(hB1.z), whh2[14], a2);
            a3 = fdot2(as_h2(hB1.w), whh2[15], a3);

            // ---- projection + pooling for step t-1 (uses h_{t-1} just read) ----
            if (t > 0) {
                const unsigned hw[8] = {hA0.x, hA0.y, hA0.z, hA0.w,
                                        hA1.x, hA1.y, hA1.z, hA1.w};
                float p0 = 0.f, p1 = 0.f;
                #pragma unroll
                for (int d = 0; d < 8; ++d) {
                    const h2 hv = as_h2(hw[d]);
                    const h2 av = __builtin_elementwise_max(hv, hv * sl2); // eval RReLU
                    if (d & 1) p1 = fdot2(av, wp2[d], p1);
                    else       p0 = fdot2(av, wp2[d], p0);
                }
                const float pa = p0 + p1;
                const float p  = pa + dpp_xor1_f(pa) + bpc;
                const float q  = p * p;
                const int tq = t - 1;
                if ((tq & 1) == 0) {
                    const float prev = Wcur + q;    // closes window tq/2 - 1
                    if (tq >= 2) {
                        float v = pool_lane ? prev : 0.0f;  // q >= 0 -> 0-pad safe
                        v = fmaxf(v, __shfl_xor(v, 16, 32));
                        v = fmaxf(v, __shfl_xor(v, 8, 32));
                        v = fmaxf(v, __shfl_xor(v, 4, 32));
                        v = fmaxf(v, __shfl_xor(v, 2, 32));
                        v = fmaxf(v, __shfl_xor(v, 1, 32));
                        if (l32 == 0) outrow[(tq >> 1) - 1] = __builtin_amdgcn_sqrtf(v);
                    }
                    Wcur = q;                       // opens window tq/2
                } else {
                    Wcur += q;
                }
            }

            // tanh(z) = 1 - 2/(exp2(z*2log2e) + 1)
            const float z  = (a0 + a1) + (a2 + a3);
            const float e  = __builtin_amdgcn_exp2f(z * 2.8853900817779268f);
            const float r  = __builtin_amdgcn_rcpf(e + 1.0f);
            const float hn = fmaf(-2.0f, r, 1.0f);
            hbuf[rowl][j] = (_Float16)hn;   // b16 write; DS FIFO orders vs next reads
        }
    }
}

extern "C" void kernel_launch(void* const* d_in, const int* in_sizes, int n_in,
                              void* d_out, int out_size, void* d_ws, size_t ws_size,
                              hipStream_t stream) {
    const float* x      = (const float*)d_in[0];
    const float* W_ih   = (const float*)d_in[1];
    const float* W_hh   = (const float*)d_in[2];
    const float* b_ih   = (const float*)d_in[3];
    const float* b_hh   = (const float*)d_in[4];
    const float* W_proj = (const float*)d_in[5];
    const float* b_proj = (const float*)d_in[6];
    float* out = (float*)d_out;

    dim3 grid(B_ROWS / 8);   // 512 blocks * 4 waves = 2048 waves = 2/SIMD
    dim3 block(256);
    hipLaunchKernelGGL(rnn_pool_kernel, grid, block, 0, stream,
                       x, W_ih, W_hh, b_ih, b_hh, W_proj, b_proj, out);
}

// Round 5
// 801.096 us; speedup vs baseline: 1.1126x; 1.1048x over previous
//
#include <hip/hip_runtime.h>
#include <math.h>

#define T_LEN   2048
#define B_ROWS  4096
#define F_IN    16
#define HID     32
#define NCH     12
#define L_OUT   1023
#define CHUNK   16
#define NCHUNK  (T_LEN / CHUNK)
#define RRELU_SLOPE 0.229f

typedef _Float16 h2 __attribute__((ext_vector_type(2)));

__device__ __forceinline__ h2 mk2(float a, float b) {
    h2 r; r.x = (_Float16)a; r.y = (_Float16)b; return r;
}
__device__ __forceinline__ h2 as_h2(unsigned u) { return __builtin_bit_cast(h2, u); }
__device__ __forceinline__ unsigned pk2(float a, float b) {
    return __builtin_bit_cast(unsigned, mk2(a, b));
}

__device__ __forceinline__ float fdot2(h2 a, h2 b, float c) {
#if __has_builtin(__builtin_amdgcn_fdot2)
    return __builtin_amdgcn_fdot2(a, b, c, false);
#else
    float r;
    asm("v_dot2_f32_f16 %0, %1, %2, %3" : "=v"(r) : "v"(a), "v"(b), "v"(c));
    return r;
#endif
}

// force a value to live in a VGPR (defeat rematerialization/sinking)
__device__ __forceinline__ void pin(h2& v) {
    unsigned u = __builtin_bit_cast(unsigned, v);
    asm("" : "+v"(u));
    v = __builtin_bit_cast(h2, u);
}

#define QP_XOR1 0xB1   // quad_perm [1,0,3,2]
template<int CTRL>
__device__ __forceinline__ unsigned dppu(unsigned v) {
    return (unsigned)__builtin_amdgcn_mov_dpp((int)v, CTRL, 0xF, 0xF, false);
}
__device__ __forceinline__ uint4 dpp_xor1_u4(uint4 v) {
    uint4 r;
    r.x = dppu<QP_XOR1>(v.x); r.y = dppu<QP_XOR1>(v.y);
    r.z = dppu<QP_XOR1>(v.z); r.w = dppu<QP_XOR1>(v.w);
    return r;
}
__device__ __forceinline__ float dpp_xor1_f(float v) {
    return __uint_as_float(dppu<QP_XOR1>(__float_as_uint(v)));
}
// fmax with a DPP-moved neighbor; invalid source lanes read 0 (bound_ctrl),
// safe because pooled q >= 0.
// row_shr:N (0x110|N): lane i <- lane i-N  => max accumulates toward lane 15/31.
// row_bcast15 (0x142): lanes 16..31 <- lane 15 (per 32-half) => lane 31 = full max.
template<int CTRL>
__device__ __forceinline__ float maxdpp(float v) {
    int s = __builtin_amdgcn_mov_dpp(__float_as_int(v), CTRL, 0xF, 0xF, true);
    return fmaxf(v, __int_as_float(s));
}

// One wave = 2 rows (32 lanes/row, lane j owns hidden unit j). All exchange is
// intra-wave: LDS fp16 broadcast reads + DPP quad-perm/row-ops (VALU pipe).
// No LDS-pipe shuffles, no __syncthreads.
__global__ __launch_bounds__(256, 2)
void rnn_pool_kernel(const float* __restrict__ x,
                     const float* __restrict__ W_ih,
                     const float* __restrict__ W_hh,
                     const float* __restrict__ b_ih,
                     const float* __restrict__ b_hh,
                     const float* __restrict__ W_proj,
                     const float* __restrict__ b_proj,
                     float* __restrict__ out)
{
    __shared__ alignas(16) _Float16 xbuf[4][2][CHUNK][F_IN];  // 4 KB
    __shared__ alignas(16) _Float16 hbuf[8][HID];             // 512 B

    const int tid  = threadIdx.x;
    const int wid  = tid >> 6;
    const int lane = tid & 63;
    const int sub  = lane >> 5;        // which of the wave's 2 rows
    const int l32  = lane & 31;
    const int par  = l32 & 1;          // k-half this lane reads (R2-proven map)
    const int rowl = (wid << 1) + sub; // row slot within block (0..7)
    const int rowBase = blockIdx.x * 8 + (wid << 1);
    const int row  = rowBase + sub;

    // ---- resident per-lane weights (fp16 pairs, parity-ordered) ----
    const int j = l32;                 // hidden unit owned by this lane
    h2 whh2[16];
    #pragma unroll
    for (int half = 0; half < 2; ++half) {
        const int kb = (half ? (1 - par) : par) * 16;  // own range first
        #pragma unroll
        for (int i = 0; i < 8; ++i)
            whh2[half * 8 + i] = mk2(W_hh[j * HID + kb + 2 * i],
                                     W_hh[j * HID + kb + 2 * i + 1]);
    }
    h2 wih2[8];
    #pragma unroll
    for (int half = 0; half < 2; ++half) {
        const int kb = (half ? (1 - par) : par) * 8;
        #pragma unroll
        for (int i = 0; i < 4; ++i)
            wih2[half * 4 + i] = mk2(W_ih[j * F_IN + kb + 2 * i],
                                     W_ih[j * F_IN + kb + 2 * i + 1]);
    }
    const float bias = b_ih[j] + b_hh[j];

    // projection: channel c = l32>>1 (clamped; lanes 24..31 dup ch11, max-safe),
    // k-half = par, so the act operand is exactly this lane's own hA registers.
    const int craw = l32 >> 1;
    const int cc   = craw < NCH ? craw : NCH - 1;
    h2 wp2[8];
    #pragma unroll
    for (int i = 0; i < 8; ++i)
        wp2[i] = mk2(W_proj[cc * HID + par * 16 + 2 * i],
                     W_proj[cc * HID + par * 16 + 2 * i + 1]);
    const float bpc = b_proj[cc];
    const h2 sl2 = mk2(RRELU_SLOPE, RRELU_SLOPE);

    // pin all weight registers (VGPR_Count=48 in R2 says they weren't resident)
    #pragma unroll
    for (int i = 0; i < 16; ++i) pin(whh2[i]);
    #pragma unroll
    for (int i = 0; i < 8; ++i)  pin(wih2[i]);
    #pragma unroll
    for (int i = 0; i < 8; ++i)  pin(wp2[i]);

    // ---- init ----
    hbuf[rowl][j] = (_Float16)0.0f;

    const float4* xsrc0 = (const float4*)(x + (size_t)(rowBase + 0) * T_LEN * F_IN);
    const float4* xsrc1 = (const float4*)(x + (size_t)(rowBase + 1) * T_LEN * F_IN);
    uint2* xw0 = (uint2*)(&xbuf[wid][0][0][0]);   // 64 x 8B = one fp16 row-chunk
    uint2* xw1 = (uint2*)(&xbuf[wid][1][0][0]);

    // prefetch chunk 0 into registers (fp32)
    float4 xs0 = xsrc0[lane];
    float4 xs1 = xsrc1[lane];

    const _Float16* hrd = &hbuf[rowl][par * 16];        // own-parity 16 halves
    const _Float16* xrd = &xbuf[wid][sub][0][par * 8];  // own-parity 8 halves

    float Wcur = 0.0f;                 // rolling LP-pool window accumulator
    float* outrow = out + (size_t)row * L_OUT;

    for (int ch = 0; ch < NCHUNK; ++ch) {
        // convert + commit staged chunk to LDS (per-wave DS FIFO ordering)
        xw0[lane] = make_uint2(pk2(xs0.x, xs0.y), pk2(xs0.z, xs0.w));
        xw1[lane] = make_uint2(pk2(xs1.x, xs1.y), pk2(xs1.z, xs1.w));
        // prefetch next chunk (clamped on the last -> uniform control flow)
        const int chn = (ch + 1 < NCHUNK) ? (ch + 1) : (NCHUNK - 1);
        xs0 = xsrc0[chn * 64 + lane];
        xs1 = xsrc1[chn * 64 + lane];

        #pragma unroll
        for (int tt = 0; tt < CHUNK; ++tt) {
            const int t = (ch << 4) + tt;

            // own-parity LDS reads (3 x b128 per lane)
            const uint4* hp = (const uint4*)hrd;
            const uint4 hA0 = hp[0];
            const uint4 hA1 = hp[1];
            const uint4* xp = (const uint4*)(xrd + tt * F_IN);
            const uint4 xA  = xp[0];

            // partner halves via DPP quad-perm (pure VALU, no LDS pipe)
            const uint4 hB0 = dpp_xor1_u4(hA0);
            const uint4 hB1 = dpp_xor1_u4(hA1);
            const uint4 xB  = dpp_xor1_u4(xA);

            // z_j = x_t . W_ih[j] + h_{t-1} . W_hh[j] + bias  (4 indep chains)
            float a0 = bias, a1 = 0.f, a2 = 0.f, a3 = 0.f;
            a0 = fdot2(as_h2(xA.x), wih2[0], a0);
            a1 = fdot2(as_h2(xA.y), wih2[1], a1);
            a2 = fdot2(as_h2(xA.z), wih2[2], a2);
            a3 = fdot2(as_h2(xA.w), wih2[3], a3);
            a0 = fdot2(as_h2(xB.x), wih2[4], a0);
            a1 = fdot2(as_h2(xB.y), wih2[5], a1);
            a2 = fdot2(as_h2(xB.z), wih2[6], a2);
            a3 = fdot2(as_h2(xB.w), wih2[7], a3);

            a0 = fdot2(as_h2(hA0.x), whh2[0],  a0);
            a1 = fdot2(as_h2(hA0.y), whh2[1],  a1);
            a2 = fdot2(as_h2(hA0.z), whh2[2],  a2);
            a3 = fdot2(as_h2(hA0.w), whh2[3],  a3);
            a0 = fdot2(as_h2(hA1.x), whh2[4],  a0);
            a1 = fdot2(as_h2(hA1.y), whh2[5],  a1);
            a2 = fdot2(as_h2(hA1.z), whh2[6],  a2);
            a3 = fdot2(as_h2(hA1.w), whh2[7],  a3);
            a0 = fdot2(as_h2(hB0.x), whh2[8],  a0);
            a1 = fdot2(as_h2(hB0.y), whh2[9],  a1);
            a2 = fdot2(as_h2(hB0.z), whh2[10], a2);
            a3 = fdot2(as_h2(hB0.w), whh2[11], a3);
            a0 = fdot2(as_h2(hB1.x), whh2[12], a0);
            a1 = fdot2(as_h2(hB1.y), whh2[13], a1);
            a2 = fdot2(as_h2(hB1.z), whh2[14], a2);
            a3 = fdot2(as_h2(hB1.w), whh2[15], a3);

            // ---- projection + pooling for step t-1 (uses h_{t-1} just read) ----
            if (t > 0) {
                const unsigned hw[8] = {hA0.x, hA0.y, hA0.z, hA0.w,
                                        hA1.x, hA1.y, hA1.z, hA1.w};
                float p0 = 0.f, p1 = 0.f;
                #pragma unroll
                for (int d = 0; d < 8; ++d) {
                    const h2 hv = as_h2(hw[d]);
                    const h2 av = __builtin_elementwise_max(hv, hv * sl2); // RReLU
                    if (d & 1) p1 = fdot2(av, wp2[d], p1);
                    else       p0 = fdot2(av, wp2[d], p0);
                }
                const float pa = p0 + p1;            // this lane's k-half partial
                const float p  = pa + dpp_xor1_f(pa) + bpc;  // + partner half
                const float q  = p * p;
                const int tq = t - 1;
                if ((tq & 1) == 0) {
                    const float prev = Wcur + q;    // closes window tq/2 - 1
                    if (tq >= 2) {
                        // channel max: row_shr chain -> lanes 15/31 hold row
                        // maxima; row_bcast15 merges row0 max into lane 31.
                        float v = prev;
                        v = maxdpp<0x118>(v);   // row_shr:8
                        v = maxdpp<0x114>(v);   // row_shr:4
                        v = maxdpp<0x112>(v);   // row_shr:2
                        v = maxdpp<0x111>(v);   // row_shr:1
                        v = maxdpp<0x142>(v);   // row_bcast15
                        if (l32 == 31) outrow[(tq >> 1) - 1] = __builtin_amdgcn_sqrtf(v);
                    }
                    Wcur = q;                       // opens window tq/2
                } else {
                    Wcur += q;
                }
            }

            // tanh(z) = 1 - 2/(exp2(z*2log2e) + 1)
            const float z  = (a0 + a1) + (a2 + a3);
            const float e  = __builtin_amdgcn_exp2f(z * 2.8853900817779268f);
            const float r  = __builtin_amdgcn_rcpf(e + 1.0f);
            const float hn = fmaf(-2.0f, r, 1.0f);
            hbuf[rowl][j] = (_Float16)hn;   // b16 write; DS FIFO orders vs next reads
        }
    }
}

extern "C" void kernel_launch(void* const* d_in, const int* in_sizes, int n_in,
                              void* d_out, int out_size, void* d_ws, size_t ws_size,
                              hipStream_t stream) {
    const float* x      = (const float*)d_in[0];
    const float* W_ih   = (const float*)d_in[1];
    const float* W_hh   = (const float*)d_in[2];
    const float* b_ih   = (const float*)d_in[3];
    const float* b_hh   = (const float*)d_in[4];
    const float* W_proj = (const float*)d_in[5];
    const float* b_proj = (const float*)d_in[6];
    float* out = (float*)d_out;

    dim3 grid(B_ROWS / 8);   // 512 blocks * 4 waves = 2048 waves = 2/SIMD
    dim3 block(256);
    hipLaunchKernelGGL(rnn_pool_kernel, grid, block, 0, stream,
                       x, W_ih, W_hh, b_ih, b_hh, W_proj, b_proj, out);
}

// Round 7
// 561.163 us; speedup vs baseline: 1.5884x; 1.4276x over previous
//
#include <hip/hip_runtime.h>
#include <math.h>

#define T_LEN   2048
#define B_ROWS  4096
#define F_IN    16
#define HID     32
#define NCH     12
#define L_OUT   1023
#define TCH     4                  // timesteps per x-staging chunk
#define NCHUNK  (T_LEN / TCH)
#define RRELU_SLOPE 0.229f

typedef _Float16 half4  __attribute__((ext_vector_type(4)));
typedef __fp16   fp16x2 __attribute__((ext_vector_type(2)));
typedef float    f32x4  __attribute__((ext_vector_type(4)));

// mfma_f32_16x16x16f16: D(16x16) = A(16x16)*B(16x16) + C
// A: row = lane&15, k = 4*(lane>>4)+i   (i = reg half index)
// B: col = lane&15, k = 4*(lane>>4)+i
// D: col = lane&15, row = 4*(lane>>4)+reg   [learn_hip m89-verified family]
__device__ __forceinline__ f32x4 mfma16(half4 a, half4 b, f32x4 c) {
    return __builtin_amdgcn_mfma_f32_16x16x16f16(a, b, c, 0, 0, 0);
}

__device__ __forceinline__ float tanh_fast(float z) {
    // tanh(z) = 1 - 2/(exp2(2*log2e*z) + 1)
    float e = __builtin_amdgcn_exp2f(z * 2.8853900817779268f);
    float r = __builtin_amdgcn_rcpf(e + 1.0f);
    return fmaf(-2.0f, r, 1.0f);
}

__device__ __forceinline__ half4 pack4(float a, float b, float c, float d) {
    unsigned lo = __builtin_bit_cast(unsigned, __builtin_amdgcn_cvt_pkrtz(a, b));
    unsigned hi = __builtin_bit_cast(unsigned, __builtin_amdgcn_cvt_pkrtz(c, d));
    uint2 u; u.x = lo; u.y = hi;
    return __builtin_bit_cast(half4, u);
}

// One wave (64 lanes) owns 16 batch rows. Orientation: Z^T = W * [x; h]:
//   A-operands = weight blocks (static, registers), B-operands = data
//   (x from LDS, h recirculated IN REGISTERS: D layout == next B layout).
// No cross-lane exchange for the recurrence; no __syncthreads (single wave).
__global__ __launch_bounds__(64, 1)
void rnn_mfma_kernel(const float* __restrict__ x,
                     const float* __restrict__ W_ih,
                     const float* __restrict__ W_hh,
                     const float* __restrict__ b_ih,
                     const float* __restrict__ b_hh,
                     const float* __restrict__ W_proj,
                     const float* __restrict__ b_proj,
                     float* __restrict__ out)
{
    __shared__ alignas(16) _Float16 xbuf[TCH][16][16];  // [t][batch][feature] 2KB
    __shared__ alignas(16) float    pbuf[64];           // pool cross-g partials

    const int lane = threadIdx.x;      // 0..63
    const int c16  = lane & 15;        // batch column (B/D col), also W-row sel
    const int g    = lane >> 4;        // k-block / D row-block
    const int rowBase = blockIdx.x * 16;

    // x staging lane mapping: 4 lanes per batch row
    const int sr = lane >> 2;          // staged row 0..15
    const int sq = lane & 3;           // feature-quad 0..3

    // ---- static A-fragments (weights), built once ----
    // A_hh[U][V]: rows u' = U*16 + (l&15), k = u = V*16 + 4g + i
    half4 Ahh[2][2];
    #pragma unroll
    for (int U = 0; U < 2; ++U)
        #pragma unroll
        for (int V = 0; V < 2; ++V)
            #pragma unroll
            for (int i = 0; i < 4; ++i)
                Ahh[U][V][i] = (_Float16)W_hh[(U*16 + c16)*HID + V*16 + 4*g + i];
    half4 Aih[2];
    #pragma unroll
    for (int U = 0; U < 2; ++U)
        #pragma unroll
        for (int i = 0; i < 4; ++i)
            Aih[U][i] = (_Float16)W_ih[(U*16 + c16)*F_IN + 4*g + i];
    half4 Ap[2];
    #pragma unroll
    for (int V = 0; V < 2; ++V)
        #pragma unroll
        for (int i = 0; i < 4; ++i)
            Ap[V][i] = (c16 < NCH) ? (_Float16)W_proj[c16*HID + V*16 + 4*g + i]
                                   : (_Float16)0.0f;

    // biases in D layout (reg r = row 4g+r)
    f32x4 biasA, biasB, biasP;
    #pragma unroll
    for (int r = 0; r < 4; ++r) {
        const int u = 4*g + r;
        biasA[r] = b_ih[u]      + b_hh[u];
        biasB[r] = b_ih[16 + u] + b_hh[16 + u];
        biasP[r] = (u < NCH) ? b_proj[u] : 0.0f;   // rows 12..15 -> p=0, q=0 (max-safe)
    }

    const half4 sl4 = {(_Float16)RRELU_SLOPE, (_Float16)RRELU_SLOPE,
                       (_Float16)RRELU_SLOPE, (_Float16)RRELU_SLOPE};

    // ---- x prefetch: chunk of TCH steps = 16 float4 per row; 4/lane ----
    const float4* xsrc = (const float4*)(x + (size_t)(rowBase + sr) * (T_LEN * F_IN));
    float4 xs[TCH];
    #pragma unroll
    for (int m = 0; m < TCH; ++m) xs[m] = xsrc[sq + 4*m];

    // recurrent state: h in B-fragment layout (lane holds units 4g+i / 16+4g+i
    // for batch c16) -- exactly what the D output gives back after tanh.
    half4 BhLo = {0, 0, 0, 0};
    half4 BhHi = {0, 0, 0, 0};
    f32x4 Wc   = {0, 0, 0, 0};         // LP-pool window accumulator (4 channels)

    float* outrow = out + (size_t)(rowBase + c16) * L_OUT;  // used by g==0 lanes

    for (int chk = 0; chk < NCHUNK; ++chk) {
        // commit staged chunk (f32 -> f16) to LDS; per-wave DS FIFO orders
        // these writes after the previous chunk's reads.
        #pragma unroll
        for (int m = 0; m < TCH; ++m)
            *(half4*)&xbuf[m][sr][sq*4] = pack4(xs[m].x, xs[m].y, xs[m].z, xs[m].w);
        const int nchk = (chk + 1 < NCHUNK) ? chk + 1 : chk;
        #pragma unroll
        for (int m = 0; m < TCH; ++m) xs[m] = xsrc[nchk*16 + sq + 4*m];

        #pragma unroll
        for (int tt = 0; tt < TCH; ++tt) {
            const int t = chk*TCH + tt;

            // B_x: x^T fragment, k=feature 4g..4g+3, col=batch c16
            const half4 Bx = *(const half4*)&xbuf[tt][c16][g*4];

            // z = W_ih*x + W_hh*h + bias   (two 16-unit blocks a/b)
            f32x4 za = mfma16(Aih[0], Bx, biasA);
            f32x4 zb = mfma16(Aih[1], Bx, biasB);
            za = mfma16(Ahh[0][0], BhLo, za);
            za = mfma16(Ahh[0][1], BhHi, za);
            zb = mfma16(Ahh[1][0], BhLo, zb);
            zb = mfma16(Ahh[1][1], BhHi, zb);

            // h = tanh(z); D reg r = unit 4g+r -> B half i = unit 4g+i: identity
            BhLo = pack4(tanh_fast(za[0]), tanh_fast(za[1]),
                         tanh_fast(za[2]), tanh_fast(za[3]));
            BhHi = pack4(tanh_fast(zb[0]), tanh_fast(zb[1]),
                         tanh_fast(zb[2]), tanh_fast(zb[3]));

            // projection: p^T = W_proj * act(h) + b   (eval-mode RReLU)
            const half4 BaLo = __builtin_elementwise_max(BhLo, BhLo * sl4);
            const half4 BaHi = __builtin_elementwise_max(BhHi, BhHi * sl4);
            f32x4 p = mfma16(Ap[0], BaLo, biasP);
            p = mfma16(Ap[1], BaHi, p);
            const f32x4 q4 = p * p;    // lane: channels 4g+r of batch c16

            // LPPool(k=3,s=2) rolling windows + channel max
            if ((t & 1) == 0) {
                if (t >= 2) {
                    const f32x4 pr = Wc + q4;   // closes window (t/2)-1
                    const float mloc = fmaxf(fmaxf(pr[0], pr[1]),
                                             fmaxf(pr[2], pr[3]));
                    pbuf[c16*4 + g] = mloc;     // 64 distinct slots, 2-way banks
                    if (g == 0) {
                        const f32x4 pv = *(const f32x4*)&pbuf[c16*4];
                        const float mm = fmaxf(fmaxf(pv[0], pv[1]),
                                               fmaxf(pv[2], pv[3]));
                        outrow[(t >> 1) - 1] = __builtin_amdgcn_sqrtf(mm);
                    }
                }
                Wc = q4;                        // opens window t/2
            } else {
                Wc = Wc + q4;
            }
        }
    }
}

extern "C" void kernel_launch(void* const* d_in, const int* in_sizes, int n_in,
                              void* d_out, int out_size, void* d_ws, size_t ws_size,
                              hipStream_t stream) {
    const float* x      = (const float*)d_in[0];
    const float* W_ih   = (const float*)d_in[1];
    const float* W_hh   = (const float*)d_in[2];
    const float* b_ih   = (const float*)d_in[3];
    const float* b_hh   = (const float*)d_in[4];
    const float* W_proj = (const float*)d_in[5];
    const float* b_proj = (const float*)d_in[6];
    float* out = (float*)d_out;

    dim3 grid(B_ROWS / 16);   // 256 blocks x 1 wave: one block per CU
    dim3 block(64);
    hipLaunchKernelGGL(rnn_mfma_kernel, grid, block, 0, stream,
                       x, W_ih, W_hh, b_ih, b_hh, W_proj, b_proj, out);
}

// Round 8
// 552.278 us; speedup vs baseline: 1.6139x; 1.0161x over previous
//
#include <hip/hip_runtime.h>
#include <math.h>

#define T_LEN   2048
#define B_ROWS  4096
#define F_IN    16
#define HID     32
#define NCH     12
#define L_OUT   1023
#define TCH     8                  // timesteps per register chunk
#define NCHUNK  (T_LEN / TCH)
#define RRELU_SLOPE 0.229f

typedef _Float16 half4 __attribute__((ext_vector_type(4)));
typedef float    f32x4 __attribute__((ext_vector_type(4)));

// mfma_f32_16x16x16f16 (R7-validated on gfx950):
// A: row = lane&15, k = 4*(lane>>4)+i
// B: col = lane&15, k = 4*(lane>>4)+i
// D: col = lane&15, row = 4*(lane>>4)+reg   -> D layout == next B layout
__device__ __forceinline__ f32x4 mfma16(half4 a, half4 b, f32x4 c) {
    return __builtin_amdgcn_mfma_f32_16x16x16f16(a, b, c, 0, 0, 0);
}

__device__ __forceinline__ float tanh_fast(float z) {
    // tanh(z) = 1 - 2/(exp2(2*log2e*z) + 1)
    float e = __builtin_amdgcn_exp2f(z * 2.8853900817779268f);
    float r = __builtin_amdgcn_rcpf(e + 1.0f);
    return fmaf(-2.0f, r, 1.0f);
}

__device__ __forceinline__ half4 pack4(float a, float b, float c, float d) {
    unsigned lo = __builtin_bit_cast(unsigned, __builtin_amdgcn_cvt_pkrtz(a, b));
    unsigned hi = __builtin_bit_cast(unsigned, __builtin_amdgcn_cvt_pkrtz(c, d));
    uint2 u; u.x = lo; u.y = hi;
    return __builtin_bit_cast(half4, u);
}

// One wave = 16 batch rows; h recirculates in registers (D layout == B layout).
// x comes straight from global into B-fragment registers (no LDS staging).
// proj+pool for step t-1 execute in the shadow of step t's h-MFMAs.
__global__ __launch_bounds__(64, 1)
void rnn_mfma_kernel(const float* __restrict__ x,
                     const float* __restrict__ W_ih,
                     const float* __restrict__ W_hh,
                     const float* __restrict__ b_ih,
                     const float* __restrict__ b_hh,
                     const float* __restrict__ W_proj,
                     const float* __restrict__ b_proj,
                     float* __restrict__ out)
{
    __shared__ alignas(16) float pbuf[64];   // pool cross-g partials (2-way banks)

    const int lane = threadIdx.x;      // 0..63
    const int c16  = lane & 15;        // batch column (B/D col)
    const int g    = lane >> 4;        // k-block / D row-block
    const int rowBase = blockIdx.x * 16;

    // ---- static A-fragments (weights), built once ----
    half4 Ahh[2][2];
    #pragma unroll
    for (int U = 0; U < 2; ++U)
        #pragma unroll
        for (int V = 0; V < 2; ++V)
            #pragma unroll
            for (int i = 0; i < 4; ++i)
                Ahh[U][V][i] = (_Float16)W_hh[(U*16 + c16)*HID + V*16 + 4*g + i];
    half4 Aih[2];
    #pragma unroll
    for (int U = 0; U < 2; ++U)
        #pragma unroll
        for (int i = 0; i < 4; ++i)
            Aih[U][i] = (_Float16)W_ih[(U*16 + c16)*F_IN + 4*g + i];
    half4 Ap[2];
    #pragma unroll
    for (int V = 0; V < 2; ++V)
        #pragma unroll
        for (int i = 0; i < 4; ++i)
            Ap[V][i] = (c16 < NCH) ? (_Float16)W_proj[c16*HID + V*16 + 4*g + i]
                                   : (_Float16)0.0f;

    // biases in D layout (reg r = row 4g+r)
    f32x4 biasA, biasB, biasP;
    #pragma unroll
    for (int r = 0; r < 4; ++r) {
        const int u = 4*g + r;
        biasA[r] = b_ih[u]      + b_hh[u];
        biasB[r] = b_ih[16 + u] + b_hh[16 + u];
        biasP[r] = (u < NCH) ? b_proj[u] : 0.0f;   // pad rows -> p=0,q=0 (max-safe)
    }

    const half4 sl4 = {(_Float16)RRELU_SLOPE, (_Float16)RRELU_SLOPE,
                       (_Float16)RRELU_SLOPE, (_Float16)RRELU_SLOPE};
    const f32x4 zero4 = {0.0f, 0.0f, 0.0f, 0.0f};

    // ---- direct-to-register x: lane (c16,g) reads x[rowBase+c16][t][4g..4g+3]
    const float4* xsrc = (const float4*)x;
    const size_t xrow = (size_t)(rowBase + c16) * T_LEN;   // in float4-quads of 4

    float4 xs[TCH];
    #pragma unroll
    for (int m = 0; m < TCH; ++m)
        xs[m] = xsrc[(xrow + m) * 4 + g];

    // recurrent state in B-fragment layout; act regs for the deferred proj
    half4 BhLo = {0,0,0,0}, BhHi = {0,0,0,0};
    half4 BaLo = {0,0,0,0}, BaHi = {0,0,0,0};
    f32x4 Wc   = zero4;                // LP-pool rolling window accumulator

    float* outrow = out + (size_t)(rowBase + c16) * L_OUT;  // g==0 lanes store

    for (int chk = 0; chk < NCHUNK; ++chk) {
        // convert chunk, precompute x-side MFMAs (h-independent)
        half4 Bxs[TCH];
        #pragma unroll
        for (int m = 0; m < TCH; ++m)
            Bxs[m] = pack4(xs[m].x, xs[m].y, xs[m].z, xs[m].w);
        f32x4 xza[TCH], xzb[TCH];
        #pragma unroll
        for (int m = 0; m < TCH; ++m) {
            xza[m] = mfma16(Aih[0], Bxs[m], biasA);
            xzb[m] = mfma16(Aih[1], Bxs[m], biasB);
        }
        // prefetch next chunk (clamped on last -> uniform)
        const int nchk = (chk + 1 < NCHUNK) ? chk + 1 : chk;
        #pragma unroll
        for (int m = 0; m < TCH; ++m)
            xs[m] = xsrc[(xrow + nchk*TCH + m) * 4 + g];

        #pragma unroll
        for (int tt = 0; tt < TCH; ++tt) {
            // ---- step t h-MFMAs: two independent pairs, combined by adds ----
            const f32x4 zaA = mfma16(Ahh[0][0], BhLo, xza[tt]);
            const f32x4 zaB = mfma16(Ahh[0][1], BhHi, zero4);
            const f32x4 zbA = mfma16(Ahh[1][0], BhLo, xzb[tt]);
            const f32x4 zbB = mfma16(Ahh[1][1], BhHi, zero4);

            // ---- shadow: projection + pooling for step t-1 ----
            if (tt > 0 || chk > 0) {
                const int tq = chk*TCH + tt - 1;
                const f32x4 pA = mfma16(Ap[0], BaLo, biasP);
                const f32x4 pB = mfma16(Ap[1], BaHi, zero4);
                const f32x4 p  = pA + pB;
                const f32x4 q4 = p * p;    // channels 4g+r of batch c16
                if ((tq & 1) == 0) {
                    const f32x4 pr = Wc + q4;      // closes window tq/2 - 1
                    if (tq >= 2) {
                        const float mloc = fmaxf(fmaxf(pr[0], pr[1]),
                                                 fmaxf(pr[2], pr[3]));
                        pbuf[c16*4 + g] = mloc;
                        if (g == 0) {
                            const f32x4 pv = *(const f32x4*)&pbuf[c16*4];
                            const float mm = fmaxf(fmaxf(pv[0], pv[1]),
                                                   fmaxf(pv[2], pv[3]));
                            outrow[(tq >> 1) - 1] = __builtin_amdgcn_sqrtf(mm);
                        }
                    }
                    Wc = q4;                        // opens window tq/2
                } else {
                    Wc = Wc + q4;
                }
            }

            // ---- combine + tanh -> h(t); act for next iter's shadow ----
            const f32x4 za = zaA + zaB;
            const f32x4 zb = zbA + zbB;
            BhLo = pack4(tanh_fast(za[0]), tanh_fast(za[1]),
                         tanh_fast(za[2]), tanh_fast(za[3]));
            BhHi = pack4(tanh_fast(zb[0]), tanh_fast(zb[1]),
                         tanh_fast(zb[2]), tanh_fast(zb[3]));
            BaLo = __builtin_elementwise_max(BhLo, BhLo * sl4);  // eval RReLU
            BaHi = __builtin_elementwise_max(BhHi, BhHi * sl4);
        }
    }
    // note: proj(T-1) is never needed -- its q only feeds a window that
    // never closes (last close is tq=2046 -> outrow[1022]).
}

extern "C" void kernel_launch(void* const* d_in, const int* in_sizes, int n_in,
                              void* d_out, int out_size, void* d_ws, size_t ws_size,
                              hipStream_t stream) {
    const float* x      = (const float*)d_in[0];
    const float* W_ih   = (const float*)d_in[1];
    const float* W_hh   = (const float*)d_in[2];
    const float* b_ih   = (const float*)d_in[3];
    const float* b_hh   = (const float*)d_in[4];
    const float* W_proj = (const float*)d_in[5];
    const float* b_proj = (const float*)d_in[6];
    float* out = (float*)d_out;

    dim3 grid(B_ROWS / 16);   // 256 independent chains, one per CU
    dim3 block(64);
    hipLaunchKernelGGL(rnn_mfma_kernel, grid, block, 0, stream,
                       x, W_ih, W_hh, b_ih, b_hh, W_proj, b_proj, out);
}

// Round 9
// 431.029 us; speedup vs baseline: 2.0679x; 1.2813x over previous
//
#include <hip/hip_runtime.h>
#include <math.h>

#define T_LEN   2048
#define B_ROWS  4096
#define F_IN    16
#define HID     32
#define NCH     12
#define L_OUT   1023
#define TCH     8                  // timesteps per chunk (= sync granularity)
#define NCHUNK  (T_LEN / TCH)
#define RRELU_SLOPE 0.229f

typedef _Float16 half4 __attribute__((ext_vector_type(4)));
typedef float    f32x4 __attribute__((ext_vector_type(4)));

// mfma_f32_16x16x16f16 (R7/R8-validated on gfx950):
// A: row = lane&15, k = 4*(lane>>4)+i
// B: col = lane&15, k = 4*(lane>>4)+i
// D: col = lane&15, row = 4*(lane>>4)+reg   -> D layout == next B layout
__device__ __forceinline__ f32x4 mfma16(half4 a, half4 b, f32x4 c) {
    return __builtin_amdgcn_mfma_f32_16x16x16f16(a, b, c, 0, 0, 0);
}

__device__ __forceinline__ float tanh_fast(float z) {
    // tanh(z) = 1 - 2/(exp2(2*log2e*z) + 1)
    float e = __builtin_amdgcn_exp2f(z * 2.8853900817779268f);
    float r = __builtin_amdgcn_rcpf(e + 1.0f);
    return fmaf(-2.0f, r, 1.0f);
}

__device__ __forceinline__ half4 pack4(float a, float b, float c, float d) {
    unsigned lo = __builtin_bit_cast(unsigned, __builtin_amdgcn_cvt_pkrtz(a, b));
    unsigned hi = __builtin_bit_cast(unsigned, __builtin_amdgcn_cvt_pkrtz(c, d));
    uint2 u; u.x = lo; u.y = hi;
    return __builtin_bit_cast(half4, u);
}

// Two waves per chain (two SIMDs):
//   wave0: sequential core only (x-MFMA precompute, h-MFMAs, tanh, pack),
//          publishes packed h to LDS ring (1 ds_write_b128/step).
//   wave1: one chunk behind -- RReLU, proj MFMAs, LP-pool, channel max, store.
// One __syncthreads per TCH-step chunk.
__global__ __launch_bounds__(128, 1)
void rnn_mfma_kernel(const float* __restrict__ x,
                     const float* __restrict__ W_ih,
                     const float* __restrict__ W_hh,
                     const float* __restrict__ b_ih,
                     const float* __restrict__ b_hh,
                     const float* __restrict__ W_proj,
                     const float* __restrict__ b_proj,
                     float* __restrict__ out)
{
    __shared__ alignas(16) uint4 hq[2][TCH][64];  // packed h double buffer, 16KB
    __shared__ alignas(16) float pbuf[64];        // wave1 cross-g pool partials

    const int tid  = threadIdx.x;
    const int wid  = tid >> 6;         // 0 = recurrence wave, 1 = proj/pool wave
    const int lane = tid & 63;
    const int c16  = lane & 15;        // batch column
    const int g    = lane >> 4;        // k-block / D row-block
    const int rowBase = blockIdx.x * 16;

    const f32x4 zero4 = {0.0f, 0.0f, 0.0f, 0.0f};
    const half4 sl4 = {(_Float16)RRELU_SLOPE, (_Float16)RRELU_SLOPE,
                       (_Float16)RRELU_SLOPE, (_Float16)RRELU_SLOPE};

    // ---- per-wave weight fragments ----
    half4 Ahh[2][2], Aih[2], Ap[2];
    f32x4 biasA = zero4, biasB = zero4, biasP = zero4;
    float4 xs[TCH];

    const float4* xsrc = (const float4*)x;
    const size_t xrow = (size_t)(rowBase + c16) * T_LEN;

    if (wid == 0) {
        #pragma unroll
        for (int U = 0; U < 2; ++U)
            #pragma unroll
            for (int V = 0; V < 2; ++V)
                #pragma unroll
                for (int i = 0; i < 4; ++i)
                    Ahh[U][V][i] = (_Float16)W_hh[(U*16 + c16)*HID + V*16 + 4*g + i];
        #pragma unroll
        for (int U = 0; U < 2; ++U)
            #pragma unroll
            for (int i = 0; i < 4; ++i)
                Aih[U][i] = (_Float16)W_ih[(U*16 + c16)*F_IN + 4*g + i];
        #pragma unroll
        for (int r = 0; r < 4; ++r) {
            const int u = 4*g + r;
            biasA[r] = b_ih[u]      + b_hh[u];
            biasB[r] = b_ih[16 + u] + b_hh[16 + u];
        }
        #pragma unroll
        for (int m = 0; m < TCH; ++m)          // prefetch chunk 0
            xs[m] = xsrc[(xrow + m) * 4 + g];
    } else {
        #pragma unroll
        for (int V = 0; V < 2; ++V)
            #pragma unroll
            for (int i = 0; i < 4; ++i)
                Ap[V][i] = (c16 < NCH) ? (_Float16)W_proj[c16*HID + V*16 + 4*g + i]
                                       : (_Float16)0.0f;
        #pragma unroll
        for (int r = 0; r < 4; ++r) {
            const int u = 4*g + r;
            biasP[r] = (u < NCH) ? b_proj[u] : 0.0f;  // pad rows -> p=0 (max-safe)
        }
    }

    half4 BhLo = {0,0,0,0}, BhHi = {0,0,0,0};   // wave0 recurrent state
    f32x4 Wc = zero4;                           // wave1 pool window accumulator
    float* outrow = out + (size_t)(rowBase + c16) * L_OUT;

    // wave1: process one TCH-chunk of published h
    auto process = [&](int c) {
        const int buf = c & 1;
        #pragma unroll
        for (int tt = 0; tt < TCH; ++tt) {
            const int t = c*TCH + tt;
            const uint4 hv = hq[buf][tt][lane];
            uint2 ulo; ulo.x = hv.x; ulo.y = hv.y;
            uint2 uhi; uhi.x = hv.z; uhi.y = hv.w;
            const half4 hLo = __builtin_bit_cast(half4, ulo);
            const half4 hHi = __builtin_bit_cast(half4, uhi);
            const half4 aLo = __builtin_elementwise_max(hLo, hLo * sl4);
            const half4 aHi = __builtin_elementwise_max(hHi, hHi * sl4);
            const f32x4 pA = mfma16(Ap[0], aLo, biasP);
            const f32x4 pB = mfma16(Ap[1], aHi, zero4);
            const f32x4 p  = pA + pB;
            const f32x4 q4 = p * p;             // channels 4g+r of batch c16
            if ((tt & 1) == 0) {                // t even (chunk base is even)
                const f32x4 pr = Wc + q4;       // closes window t/2 - 1
                if (t >= 2) {
                    const float mloc = fmaxf(fmaxf(pr[0], pr[1]),
                                             fmaxf(pr[2], pr[3]));
                    pbuf[c16*4 + g] = mloc;     // wave1-internal, DS FIFO ordered
                    if (g == 0) {
                        const f32x4 pv = *(const f32x4*)&pbuf[c16*4];
                        const float mm = fmaxf(fmaxf(pv[0], pv[1]),
                                               fmaxf(pv[2], pv[3]));
                        outrow[(t >> 1) - 1] = __builtin_amdgcn_sqrtf(mm);
                    }
                }
                Wc = q4;                        // opens window t/2
            } else {
                Wc = Wc + q4;
            }
        }
    };

    for (int chk = 0; chk < NCHUNK; ++chk) {
        if (wid == 0) {
            // x-side: convert + precompute x-MFMAs (h-independent)
            half4 Bxs[TCH];
            #pragma unroll
            for (int m = 0; m < TCH; ++m)
                Bxs[m] = pack4(xs[m].x, xs[m].y, xs[m].z, xs[m].w);
            f32x4 xza[TCH], xzb[TCH];
            #pragma unroll
            for (int m = 0; m < TCH; ++m) {
                xza[m] = mfma16(Aih[0], Bxs[m], biasA);
                xzb[m] = mfma16(Aih[1], Bxs[m], biasB);
            }
            const int nchk = (chk + 1 < NCHUNK) ? chk + 1 : chk;
            #pragma unroll
            for (int m = 0; m < TCH; ++m)
                xs[m] = xsrc[(xrow + nchk*TCH + m) * 4 + g];

            // sequential core
            #pragma unroll
            for (int tt = 0; tt < TCH; ++tt) {
                const f32x4 zaA = mfma16(Ahh[0][0], BhLo, xza[tt]);
                const f32x4 zaB = mfma16(Ahh[0][1], BhHi, zero4);
                const f32x4 zbA = mfma16(Ahh[1][0], BhLo, xzb[tt]);
                const f32x4 zbB = mfma16(Ahh[1][1], BhHi, zero4);
                const f32x4 za = zaA + zaB;
                const f32x4 zb = zbA + zbB;
                BhLo = pack4(tanh_fast(za[0]), tanh_fast(za[1]),
                             tanh_fast(za[2]), tanh_fast(za[3]));
                BhHi = pack4(tanh_fast(zb[0]), tanh_fast(zb[1]),
                             tanh_fast(zb[2]), tanh_fast(zb[3]));
                uint2 lo = __builtin_bit_cast(uint2, BhLo);
                uint2 hi = __builtin_bit_cast(uint2, BhHi);
                hq[chk & 1][tt][lane] = make_uint4(lo.x, lo.y, hi.x, hi.y);
            }
        } else {
            if (chk > 0) process(chk - 1);
        }
        __syncthreads();   // publishes hq[chk&1]; frees hq[(chk-1)&1]
    }
    if (wid == 1) process(NCHUNK - 1);
}

extern "C" void kernel_launch(void* const* d_in, const int* in_sizes, int n_in,
                              void* d_out, int out_size, void* d_ws, size_t ws_size,
                              hipStream_t stream) {
    const float* x      = (const float*)d_in[0];
    const float* W_ih   = (const float*)d_in[1];
    const float* W_hh   = (const float*)d_in[2];
    const float* b_ih   = (const float*)d_in[3];
    const float* b_hh   = (const float*)d_in[4];
    const float* W_proj = (const float*)d_in[5];
    const float* b_proj = (const float*)d_in[6];
    float* out = (float*)d_out;

    dim3 grid(B_ROWS / 16);   // 256 chains; 2 waves (2 SIMDs) per chain
    dim3 block(128);
    hipLaunchKernelGGL(rnn_mfma_kernel, grid, block, 0, stream,
                       x, W_ih, W_hh, b_ih, b_hh, W_proj, b_proj, out);
}

// Round 10
// 410.355 us; speedup vs baseline: 2.1721x; 1.0504x over previous
//
#include <hip/hip_runtime.h>
#include <math.h>

#define T_LEN   2048
#define B_ROWS  4096
#define F_IN    16
#define HID     32
#define NCH     12
#define L_OUT   1023
#define TCH     8                  // timesteps per chunk (= sync granularity)
#define NCHUNK  (T_LEN / TCH)
#define RRELU_SLOPE 0.229f

typedef _Float16 half4 __attribute__((ext_vector_type(4)));
typedef float    f32x4 __attribute__((ext_vector_type(4)));

// mfma_f32_16x16x16f16 (R7-R9 validated on gfx950):
// A: row = lane&15, k = 4*(lane>>4)+i
// B: col = lane&15, k = 4*(lane>>4)+i
// D: col = lane&15, row = 4*(lane>>4)+reg   -> D layout == next B layout
__device__ __forceinline__ f32x4 mfma16(half4 a, half4 b, f32x4 c) {
    return __builtin_amdgcn_mfma_f32_16x16x16f16(a, b, c, 0, 0, 0);
}

__device__ __forceinline__ float tanh_fast(float z) {
    // tanh(z) = 1 - 2/(exp2(2*log2e*z) + 1)
    float e = __builtin_amdgcn_exp2f(z * 2.8853900817779268f);
    float r = __builtin_amdgcn_rcpf(e + 1.0f);
    return fmaf(-2.0f, r, 1.0f);
}

__device__ __forceinline__ half4 pack4(float a, float b, float c, float d) {
    unsigned lo = __builtin_bit_cast(unsigned, __builtin_amdgcn_cvt_pkrtz(a, b));
    unsigned hi = __builtin_bit_cast(unsigned, __builtin_amdgcn_cvt_pkrtz(c, d));
    uint2 u; u.x = lo; u.y = hi;
    return __builtin_bit_cast(half4, u);
}

__device__ __forceinline__ uint4 u4(f32x4 v) { return __builtin_bit_cast(uint4, v); }
__device__ __forceinline__ f32x4 f4(uint4 v) { return __builtin_bit_cast(f32x4, v); }

// Three waves per chain (three SIMDs):
//   wave0: irreducible recurrence only (h-MFMAs, tanh, pack, publish h).
//   wave1: x-prep one chunk ahead (global loads prefetched a further chunk
//          ahead, f16 pack, x-MFMAs, publish xz = W_ih*x + bias to LDS).
//   wave2: one chunk behind -- RReLU, proj MFMAs, LP-pool, channel max, store.
// One __syncthreads per TCH-step chunk; chunk loop unrolled x2 so all LDS
// buffer indices and xs ping-pong register sets are compile-time static.
__global__ __launch_bounds__(192, 1)
void rnn_mfma_kernel(const float* __restrict__ x,
                     const float* __restrict__ W_ih,
                     const float* __restrict__ W_hh,
                     const float* __restrict__ b_ih,
                     const float* __restrict__ b_hh,
                     const float* __restrict__ W_proj,
                     const float* __restrict__ b_proj,
                     float* __restrict__ out)
{
    __shared__ alignas(16) uint4 hqs[2][TCH][64];    // packed h,  16 KB
    __shared__ alignas(16) uint4 xza_s[2][TCH][64];  // xz lo block, 16 KB (f32x4)
    __shared__ alignas(16) uint4 xzb_s[2][TCH][64];  // xz hi block, 16 KB
    __shared__ alignas(16) float pbuf[64];           // wave2 cross-g partials

    const int tid  = threadIdx.x;
    const int wid  = tid >> 6;         // 0=recurrence, 1=x-prep, 2=proj/pool
    const int lane = tid & 63;
    const int c16  = lane & 15;        // batch column
    const int g    = lane >> 4;        // k-block / D row-block
    const int rowBase = blockIdx.x * 16;

    const f32x4 zero4 = {0.0f, 0.0f, 0.0f, 0.0f};
    const half4 sl4 = {(_Float16)RRELU_SLOPE, (_Float16)RRELU_SLOPE,
                       (_Float16)RRELU_SLOPE, (_Float16)RRELU_SLOPE};

    const float4* xsrc = (const float4*)x;
    const size_t xrow = (size_t)(rowBase + c16) * T_LEN;
    float* outrow = out + (size_t)(rowBase + c16) * L_OUT;

    // ---- per-wave weight fragments ----
    half4 Ahh[2][2], Aih[2], Ap[2];
    f32x4 biasA = zero4, biasB = zero4, biasP = zero4;
    float4 xsA[TCH], xsB[TCH];         // wave1 load ping-pong

    if (wid == 0) {
        #pragma unroll
        for (int U = 0; U < 2; ++U)
            #pragma unroll
            for (int V = 0; V < 2; ++V)
                #pragma unroll
                for (int i = 0; i < 4; ++i)
                    Ahh[U][V][i] = (_Float16)W_hh[(U*16 + c16)*HID + V*16 + 4*g + i];
    } else if (wid == 1) {
        #pragma unroll
        for (int U = 0; U < 2; ++U)
            #pragma unroll
            for (int i = 0; i < 4; ++i)
                Aih[U][i] = (_Float16)W_ih[(U*16 + c16)*F_IN + 4*g + i];
        #pragma unroll
        for (int r = 0; r < 4; ++r) {
            const int u = 4*g + r;
            biasA[r] = b_ih[u]      + b_hh[u];
            biasB[r] = b_ih[16 + u] + b_hh[16 + u];
        }
    } else {
        #pragma unroll
        for (int V = 0; V < 2; ++V)
            #pragma unroll
            for (int i = 0; i < 4; ++i)
                Ap[V][i] = (c16 < NCH) ? (_Float16)W_proj[c16*HID + V*16 + 4*g + i]
                                       : (_Float16)0.0f;
        #pragma unroll
        for (int r = 0; r < 4; ++r) {
            const int u = 4*g + r;
            biasP[r] = (u < NCH) ? b_proj[u] : 0.0f;  // pad rows -> p=0 (max-safe)
        }
    }

    half4 BhLo = {0,0,0,0}, BhHi = {0,0,0,0};   // wave0 recurrent state
    f32x4 Wc = zero4;                           // wave2 pool window accumulator

    // ---- wave1 helpers (buf/regset become constants after inlining) ----
    auto w1_load = [&](int c, float4* xs) {
        const int cc = (c < NCHUNK) ? c : NCHUNK - 1;
        #pragma unroll
        for (int m = 0; m < TCH; ++m)
            xs[m] = xsrc[(xrow + cc*TCH + m) * 4 + g];
    };
    auto w1_compute = [&](int buf, const float4* xs) {
        #pragma unroll
        for (int m = 0; m < TCH; ++m) {
            const half4 Bx = pack4(xs[m].x, xs[m].y, xs[m].z, xs[m].w);
            xza_s[buf][m][lane] = u4(mfma16(Aih[0], Bx, biasA));
            xzb_s[buf][m][lane] = u4(mfma16(Aih[1], Bx, biasB));
        }
    };

    // ---- wave0: one chunk of the sequential core ----
    auto w0_chunk = [&](int buf) {
        uint4 ra[2], rb[2];
        ra[0] = xza_s[buf][0][lane]; rb[0] = xzb_s[buf][0][lane];
        ra[1] = xza_s[buf][1][lane]; rb[1] = xzb_s[buf][1][lane];
        #pragma unroll
        for (int tt = 0; tt < TCH; ++tt) {
            const f32x4 xza = f4(ra[tt & 1]);
            const f32x4 xzb = f4(rb[tt & 1]);
            const f32x4 zaA = mfma16(Ahh[0][0], BhLo, xza);
            const f32x4 zaB = mfma16(Ahh[0][1], BhHi, zero4);
            const f32x4 zbA = mfma16(Ahh[1][0], BhLo, xzb);
            const f32x4 zbB = mfma16(Ahh[1][1], BhHi, zero4);
            if (tt + 2 < TCH) {                 // prefetch 2 steps ahead
                ra[tt & 1] = xza_s[buf][tt + 2][lane];
                rb[tt & 1] = xzb_s[buf][tt + 2][lane];
            }
            const f32x4 za = zaA + zaB;
            const f32x4 zb = zbA + zbB;
            BhLo = pack4(tanh_fast(za[0]), tanh_fast(za[1]),
                         tanh_fast(za[2]), tanh_fast(za[3]));
            BhHi = pack4(tanh_fast(zb[0]), tanh_fast(zb[1]),
                         tanh_fast(zb[2]), tanh_fast(zb[3]));
            uint2 lo = __builtin_bit_cast(uint2, BhLo);
            uint2 hi = __builtin_bit_cast(uint2, BhHi);
            hqs[buf][tt][lane] = make_uint4(lo.x, lo.y, hi.x, hi.y);
        }
    };

    // ---- wave2: proj + pool for one published chunk ----
    auto w2_process = [&](int c, int buf) {
        #pragma unroll
        for (int tt = 0; tt < TCH; ++tt) {
            const int t = c*TCH + tt;
            const uint4 hv = hqs[buf][tt][lane];
            uint2 ulo; ulo.x = hv.x; ulo.y = hv.y;
            uint2 uhi; uhi.x = hv.z; uhi.y = hv.w;
            const half4 hLo = __builtin_bit_cast(half4, ulo);
            const half4 hHi = __builtin_bit_cast(half4, uhi);
            const half4 aLo = __builtin_elementwise_max(hLo, hLo * sl4);
            const half4 aHi = __builtin_elementwise_max(hHi, hHi * sl4);
            const f32x4 pA = mfma16(Ap[0], aLo, biasP);
            const f32x4 pB = mfma16(Ap[1], aHi, zero4);
            const f32x4 p  = pA + pB;
            const f32x4 q4 = p * p;             // channels 4g+r of batch c16
            if ((tt & 1) == 0) {                // t even (chunk base even)
                const f32x4 pr = Wc + q4;       // closes window t/2 - 1
                if (t >= 2) {
                    const float mloc = fmaxf(fmaxf(pr[0], pr[1]),
                                             fmaxf(pr[2], pr[3]));
                    pbuf[c16*4 + g] = mloc;     // intra-wave, DS FIFO ordered
                    if (g == 0) {
                        const f32x4 pv = *(const f32x4*)&pbuf[c16*4];
                        const float mm = fmaxf(fmaxf(pv[0], pv[1]),
                                               fmaxf(pv[2], pv[3]));
                        outrow[(t >> 1) - 1] = __builtin_amdgcn_sqrtf(mm);
                    }
                }
                Wc = q4;                        // opens window t/2
            } else {
                Wc = Wc + q4;
            }
        }
    };

    // ---- prologue: wave1 fills chunk 0 (buf0) and prefetches chunk 1 ----
    if (wid == 1) {
        w1_load(0, xsA);
        w1_compute(0, xsA);
        w1_load(1, xsA);
    }
    __syncthreads();

    // ---- main loop, unrolled x2 (NCHUNK even) ----
    for (int cc = 0; cc < NCHUNK; cc += 2) {
        // sub A: chunk cc (buffers 0)
        if (wid == 0) {
            w0_chunk(0);
        } else if (wid == 1) {
            w1_load(cc + 2, xsB);      // issue loads first (latency cover)
            w1_compute(1, xsA);        // xz for chunk cc+1 -> buf1
        } else {
            if (cc > 0) w2_process(cc - 1, 1);
        }
        __syncthreads();
        // sub B: chunk cc+1 (buffers 1)
        if (wid == 0) {
            w0_chunk(1);
        } else if (wid == 1) {
            w1_load(cc + 3, xsA);
            w1_compute(0, xsB);        // xz for chunk cc+2 -> buf0
        } else {
            w2_process(cc, 0);
        }
        __syncthreads();
    }
    if (wid == 2) w2_process(NCHUNK - 1, 1);
}

extern "C" void kernel_launch(void* const* d_in, const int* in_sizes, int n_in,
                              void* d_out, int out_size, void* d_ws, size_t ws_size,
                              hipStream_t stream) {
    const float* x      = (const float*)d_in[0];
    const float* W_ih   = (const float*)d_in[1];
    const float* W_hh   = (const float*)d_in[2];
    const float* b_ih   = (const float*)d_in[3];
    const float* b_hh   = (const float*)d_in[4];
    const float* W_proj = (const float*)d_in[5];
    const float* b_proj = (const float*)d_in[6];
    float* out = (float*)d_out;

    dim3 grid(B_ROWS / 16);   // 256 chains; 3 waves (3 SIMDs) per chain
    dim3 block(192);
    hipLaunchKernelGGL(rnn_mfma_kernel, grid, block, 0, stream,
                       x, W_ih, W_hh, b_ih, b_hh, W_proj, b_proj, out);
}

// Round 11
// 322.617 us; speedup vs baseline: 2.7628x; 1.2720x over previous
//
#include <hip/hip_runtime.h>
#include <math.h>

#define T_LEN   2048
#define B_ROWS  4096
#define F_IN    16
#define HID     32
#define NCH     12
#define L_OUT   1023
#define TCH     16                 // timesteps per chunk (= sync granularity)
#define NCHUNK  (T_LEN / TCH)
#define RRELU_SLOPE 0.229f
#define ZSCALE  2.8853900817779268f   // 2*log2(e), folded into W_ih/W_hh/biases

typedef _Float16 half4 __attribute__((ext_vector_type(4)));
typedef float    f32x4 __attribute__((ext_vector_type(4)));

// mfma_f32_16x16x16f16 (R7-R10 validated on gfx950):
// A: row = lane&15, k = 4*(lane>>4)+i
// B: col = lane&15, k = 4*(lane>>4)+i
// D: col = lane&15, row = 4*(lane>>4)+reg   -> D layout == next B layout
__device__ __forceinline__ f32x4 mfma16(half4 a, half4 b, f32x4 c) {
    return __builtin_amdgcn_mfma_f32_16x16x16f16(a, b, c, 0, 0, 0);
}

// z' arrives PRE-SCALED by 2*log2(e): tanh = 1 - 2/(exp2(z') + 1)
__device__ __forceinline__ float act_fast(float zs) {
    float e = __builtin_amdgcn_exp2f(zs);
    float r = __builtin_amdgcn_rcpf(e + 1.0f);
    return fmaf(-2.0f, r, 1.0f);
}

__device__ __forceinline__ half4 pack4(float a, float b, float c, float d) {
    unsigned lo = __builtin_bit_cast(unsigned, __builtin_amdgcn_cvt_pkrtz(a, b));
    unsigned hi = __builtin_bit_cast(unsigned, __builtin_amdgcn_cvt_pkrtz(c, d));
    uint2 u; u.x = lo; u.y = hi;
    return __builtin_bit_cast(half4, u);
}

__device__ __forceinline__ uint4 u4(f32x4 v) { return __builtin_bit_cast(uint4, v); }
__device__ __forceinline__ f32x4 f4(uint4 v) { return __builtin_bit_cast(f32x4, v); }

// Three waves per chain (three SIMDs):
//   wave0: irreducible recurrence (C-chained h-MFMAs, exp2-tanh, pack, publish).
//   wave1: x-prep one chunk ahead (prefetched global loads, f16 pack, x-MFMAs
//          with PRE-SCALED Aih/bias, publish xz' = 2log2e*(W_ih*x+b) to LDS).
//   wave2: one chunk behind -- RReLU, proj MFMAs, LP-pool, channel max, store.
__global__ __launch_bounds__(192, 1)
void rnn_mfma_kernel(const float* __restrict__ x,
                     const float* __restrict__ W_ih,
                     const float* __restrict__ W_hh,
                     const float* __restrict__ b_ih,
                     const float* __restrict__ b_hh,
                     const float* __restrict__ W_proj,
                     const float* __restrict__ b_proj,
                     float* __restrict__ out)
{
    __shared__ alignas(16) uint4 hqs[2][TCH][64];    // packed h,   32 KB
    __shared__ alignas(16) uint4 xza_s[2][TCH][64];  // xz' lo blk, 32 KB (f32x4)
    __shared__ alignas(16) uint4 xzb_s[2][TCH][64];  // xz' hi blk, 32 KB
    __shared__ alignas(16) float pbuf[64];           // wave2 cross-g partials

    const int tid  = threadIdx.x;
    const int wid  = tid >> 6;         // 0=recurrence, 1=x-prep, 2=proj/pool
    const int lane = tid & 63;
    const int c16  = lane & 15;        // batch column
    const int g    = lane >> 4;        // k-block / D row-block
    const int rowBase = blockIdx.x * 16;

    const f32x4 zero4 = {0.0f, 0.0f, 0.0f, 0.0f};
    const half4 sl4 = {(_Float16)RRELU_SLOPE, (_Float16)RRELU_SLOPE,
                       (_Float16)RRELU_SLOPE, (_Float16)RRELU_SLOPE};

    const float4* xsrc = (const float4*)x;
    const size_t xrow = (size_t)(rowBase + c16) * T_LEN;
    float* outrow = out + (size_t)(rowBase + c16) * L_OUT;

    // ---- per-wave weight fragments ----
    half4 Ahh[2][2], Aih[2], Ap[2];
    f32x4 biasA = zero4, biasB = zero4, biasP = zero4;
    float4 xsA[TCH], xsB[TCH];         // wave1 load ping-pong

    if (wid == 0) {
        #pragma unroll
        for (int U = 0; U < 2; ++U)
            #pragma unroll
            for (int V = 0; V < 2; ++V)
                #pragma unroll
                for (int i = 0; i < 4; ++i)
                    Ahh[U][V][i] = (_Float16)(ZSCALE *
                        W_hh[(U*16 + c16)*HID + V*16 + 4*g + i]);
    } else if (wid == 1) {
        #pragma unroll
        for (int U = 0; U < 2; ++U)
            #pragma unroll
            for (int i = 0; i < 4; ++i)
                Aih[U][i] = (_Float16)(ZSCALE *
                    W_ih[(U*16 + c16)*F_IN + 4*g + i]);
        #pragma unroll
        for (int r = 0; r < 4; ++r) {
            const int u = 4*g + r;
            biasA[r] = ZSCALE * (b_ih[u]      + b_hh[u]);
            biasB[r] = ZSCALE * (b_ih[16 + u] + b_hh[16 + u]);
        }
    } else {
        #pragma unroll
        for (int V = 0; V < 2; ++V)
            #pragma unroll
            for (int i = 0; i < 4; ++i)
                Ap[V][i] = (c16 < NCH) ? (_Float16)W_proj[c16*HID + V*16 + 4*g + i]
                                       : (_Float16)0.0f;
        #pragma unroll
        for (int r = 0; r < 4; ++r) {
            const int u = 4*g + r;
            biasP[r] = (u < NCH) ? b_proj[u] : 0.0f;  // pad rows -> p=0 (max-safe)
        }
    }

    half4 BhLo = {0,0,0,0}, BhHi = {0,0,0,0};   // wave0 recurrent state
    f32x4 Wc = zero4;                           // wave2 pool window accumulator

    // ---- wave1 helpers ----
    auto w1_load = [&](int c, float4* xs) {
        const int cc = (c < NCHUNK) ? c : NCHUNK - 1;
        #pragma unroll
        for (int m = 0; m < TCH; ++m)
            xs[m] = xsrc[(xrow + cc*TCH + m) * 4 + g];
    };
    auto w1_compute = [&](int buf, const float4* xs) {
        #pragma unroll
        for (int m = 0; m < TCH; ++m) {
            const half4 Bx = pack4(xs[m].x, xs[m].y, xs[m].z, xs[m].w);
            xza_s[buf][m][lane] = u4(mfma16(Aih[0], Bx, biasA));
            xzb_s[buf][m][lane] = u4(mfma16(Aih[1], Bx, biasB));
        }
    };

    // ---- wave0: one chunk of the sequential core (4-deep xz prefetch) ----
    auto w0_chunk = [&](int buf) {
        uint4 ra[4], rb[4];
        #pragma unroll
        for (int i = 0; i < 4; ++i) {
            ra[i] = xza_s[buf][i][lane];
            rb[i] = xzb_s[buf][i][lane];
        }
        #pragma unroll
        for (int tt = 0; tt < TCH; ++tt) {
            const f32x4 xza = f4(ra[tt & 3]);
            const f32x4 xzb = f4(rb[tt & 3]);
            // C-chained accumulation: za = Ahh01*BhHi + (Ahh00*BhLo + xza)
            f32x4 za = mfma16(Ahh[0][0], BhLo, xza);
            f32x4 zb = mfma16(Ahh[1][0], BhLo, xzb);
            za = mfma16(Ahh[0][1], BhHi, za);
            zb = mfma16(Ahh[1][1], BhHi, zb);
            if (tt + 4 < TCH) {                 // prefetch 4 steps ahead
                ra[tt & 3] = xza_s[buf][tt + 4][lane];
                rb[tt & 3] = xzb_s[buf][tt + 4][lane];
            }
            BhLo = pack4(act_fast(za[0]), act_fast(za[1]),
                         act_fast(za[2]), act_fast(za[3]));
            BhHi = pack4(act_fast(zb[0]), act_fast(zb[1]),
                         act_fast(zb[2]), act_fast(zb[3]));
            uint2 lo = __builtin_bit_cast(uint2, BhLo);
            uint2 hi = __builtin_bit_cast(uint2, BhHi);
            hqs[buf][tt][lane] = make_uint4(lo.x, lo.y, hi.x, hi.y);
        }
    };

    // ---- wave2: proj + pool for one published chunk ----
    auto w2_process = [&](int c, int buf) {
        #pragma unroll
        for (int tt = 0; tt < TCH; ++tt) {
            const int t = c*TCH + tt;
            const uint4 hv = hqs[buf][tt][lane];
            uint2 ulo; ulo.x = hv.x; ulo.y = hv.y;
            uint2 uhi; uhi.x = hv.z; uhi.y = hv.w;
            const half4 hLo = __builtin_bit_cast(half4, ulo);
            const half4 hHi = __builtin_bit_cast(half4, uhi);
            const half4 aLo = __builtin_elementwise_max(hLo, hLo * sl4);
            const half4 aHi = __builtin_elementwise_max(hHi, hHi * sl4);
            f32x4 p = mfma16(Ap[0], aLo, biasP);
            p = mfma16(Ap[1], aHi, p);          // C-chained
            const f32x4 q4 = p * p;             // channels 4g+r of batch c16
            if ((tt & 1) == 0) {                // t even (chunk base even)
                const f32x4 pr = Wc + q4;       // closes window t/2 - 1
                if (t >= 2) {
                    const float mloc = fmaxf(fmaxf(pr[0], pr[1]),
                                             fmaxf(pr[2], pr[3]));
                    pbuf[c16*4 + g] = mloc;     // intra-wave, DS FIFO ordered
                    if (g == 0) {
                        const f32x4 pv = *(const f32x4*)&pbuf[c16*4];
                        const float mm = fmaxf(fmaxf(pv[0], pv[1]),
                                               fmaxf(pv[2], pv[3]));
                        outrow[(t >> 1) - 1] = __builtin_amdgcn_sqrtf(mm);
                    }
                }
                Wc = q4;                        // opens window t/2
            } else {
                Wc = Wc + q4;
            }
        }
    };

    // ---- prologue: wave1 fills chunk 0 (buf0) and prefetches chunk 1 ----
    if (wid == 1) {
        w1_load(0, xsA);
        w1_compute(0, xsA);
        w1_load(1, xsA);
    }
    __syncthreads();

    // ---- main loop, unrolled x2 (NCHUNK = 128, even) ----
    for (int cc = 0; cc < NCHUNK; cc += 2) {
        // sub A: chunk cc (buffers 0)
        if (wid == 0) {
            w0_chunk(0);
        } else if (wid == 1) {
            w1_load(cc + 2, xsB);      // issue loads first (latency cover)
            w1_compute(1, xsA);        // xz' for chunk cc+1 -> buf1
        } else {
            if (cc > 0) w2_process(cc - 1, 1);
        }
        __syncthreads();
        // sub B: chunk cc+1 (buffers 1)
        if (wid == 0) {
            w0_chunk(1);
        } else if (wid == 1) {
            w1_load(cc + 3, xsA);
            w1_compute(0, xsB);        // xz' for chunk cc+2 -> buf0
        } else {
            w2_process(cc, 0);
        }
        __syncthreads();
    }
    if (wid == 2) w2_process(NCHUNK - 1, 1);
}

extern "C" void kernel_launch(void* const* d_in, const int* in_sizes, int n_in,
                              void* d_out, int out_size, void* d_ws, size_t ws_size,
                              hipStream_t stream) {
    const float* x      = (const float*)d_in[0];
    const float* W_ih   = (const float*)d_in[1];
    const float* W_hh   = (const float*)d_in[2];
    const float* b_ih   = (const float*)d_in[3];
    const float* b_hh   = (const float*)d_in[4];
    const float* W_proj = (const float*)d_in[5];
    const float* b_proj = (const float*)d_in[6];
    float* out = (float*)d_out;

    dim3 grid(B_ROWS / 16);   // 256 chains; 3 waves (3 SIMDs) per chain
    dim3 block(192);
    hipLaunchKernelGGL(rnn_mfma_kernel, grid, block, 0, stream,
                       x, W_ih, W_hh, b_ih, b_hh, W_proj, b_proj, out);
}

// Round 12
// 309.429 us; speedup vs baseline: 2.8806x; 1.0426x over previous
//
#include <hip/hip_runtime.h>
#include <math.h>

#define T_LEN   2048
#define B_ROWS  4096
#define F_IN    16
#define HID     32
#define NCH     12
#define L_OUT   1023
#define TCH     16                 // timesteps per chunk (= sync granularity)
#define NCHUNK  (T_LEN / TCH)
#define RRELU_SLOPE 0.229f
#define ZSCALE  2.8853900817779268f   // 2*log2(e), folded into W_ih/W_hh/biases

typedef _Float16 half4 __attribute__((ext_vector_type(4)));
typedef _Float16 half8 __attribute__((ext_vector_type(8)));
typedef float    f32x4 __attribute__((ext_vector_type(4)));

// mfma_f32_16x16x16f16 (R7-R11 validated on gfx950):
// A: row = lane&15, k = 4*(lane>>4)+i
// B: col = lane&15, k = 4*(lane>>4)+i
// D: col = lane&15, row = 4*(lane>>4)+reg   -> D layout == next B layout
__device__ __forceinline__ f32x4 mfma16(half4 a, half4 b, f32x4 c) {
    return __builtin_amdgcn_mfma_f32_16x16x16f16(a, b, c, 0, 0, 0);
}

// K=32 fragment model (inference from m156/m162 tr-read layout): the x32
// fragment = concat of two x16 fragments -- elems 0-3: k=4g+i, elems 4-7:
// k=16+4g+i. Fallback: chained x16 pair (R11-proven) if builtin missing.
__device__ __forceinline__ f32x4 hmfma32(half8 a, half8 b, f32x4 c) {
#if __has_builtin(__builtin_amdgcn_mfma_f32_16x16x32_f16)
    return __builtin_amdgcn_mfma_f32_16x16x32_f16(a, b, c, 0, 0, 0);
#else
    const uint4 ua = __builtin_bit_cast(uint4, a);
    const uint4 ub = __builtin_bit_cast(uint4, b);
    uint2 t;
    t.x = ua.x; t.y = ua.y; const half4 alo = __builtin_bit_cast(half4, t);
    t.x = ua.z; t.y = ua.w; const half4 ahi = __builtin_bit_cast(half4, t);
    t.x = ub.x; t.y = ub.y; const half4 blo = __builtin_bit_cast(half4, t);
    t.x = ub.z; t.y = ub.w; const half4 bhi = __builtin_bit_cast(half4, t);
    return mfma16(ahi, bhi, mfma16(alo, blo, c));
#endif
}

// z' arrives PRE-SCALED by 2*log2(e): tanh = 1 - 2/(exp2(z') + 1)
__device__ __forceinline__ float act_fast(float zs) {
    float e = __builtin_amdgcn_exp2f(zs);
    float r = __builtin_amdgcn_rcpf(e + 1.0f);
    return fmaf(-2.0f, r, 1.0f);
}

__device__ __forceinline__ unsigned pk2u(float a, float b) {
    return __builtin_bit_cast(unsigned, __builtin_amdgcn_cvt_pkrtz(a, b));
}
__device__ __forceinline__ half4 pack4(float a, float b, float c, float d) {
    uint2 u; u.x = pk2u(a, b); u.y = pk2u(c, d);
    return __builtin_bit_cast(half4, u);
}

__device__ __forceinline__ uint4 u4(f32x4 v) { return __builtin_bit_cast(uint4, v); }
__device__ __forceinline__ f32x4 f4(uint4 v) { return __builtin_bit_cast(f32x4, v); }

// Three waves per chain (three SIMDs):
//   wave0: irreducible recurrence (one K=32 MFMA per 16-unit block, exp2-tanh,
//          pack, publish h).
//   wave1: x-prep one chunk ahead (prefetched loads, f16 pack, K=16 x-MFMAs
//          with PRE-SCALED Aih/bias, publish xz' to LDS).
//   wave2: one chunk behind -- RReLU, one K=32 proj MFMA, LP-pool, max, store.
__global__ __launch_bounds__(192, 1)
void rnn_mfma_kernel(const float* __restrict__ x,
                     const float* __restrict__ W_ih,
                     const float* __restrict__ W_hh,
                     const float* __restrict__ b_ih,
                     const float* __restrict__ b_hh,
                     const float* __restrict__ W_proj,
                     const float* __restrict__ b_proj,
                     float* __restrict__ out)
{
    __shared__ alignas(16) uint4 hqs[2][TCH][64];    // packed h,   32 KB
    __shared__ alignas(16) uint4 xza_s[2][TCH][64];  // xz' lo blk, 32 KB (f32x4)
    __shared__ alignas(16) uint4 xzb_s[2][TCH][64];  // xz' hi blk, 32 KB
    __shared__ alignas(16) float pbuf[64];           // wave2 cross-g partials

    const int tid  = threadIdx.x;
    const int wid  = tid >> 6;         // 0=recurrence, 1=x-prep, 2=proj/pool
    const int lane = tid & 63;
    const int c16  = lane & 15;        // batch column
    const int g    = lane >> 4;        // k-block / D row-block
    const int rowBase = blockIdx.x * 16;

    const f32x4 zero4 = {0.0f, 0.0f, 0.0f, 0.0f};

    const float4* xsrc = (const float4*)x;
    const size_t xrow = (size_t)(rowBase + c16) * T_LEN;
    float* outrow = out + (size_t)(rowBase + c16) * L_OUT;

    // ---- per-wave weight fragments ----
    half8 AhhF[2];                     // K=32 fragments for the two unit-blocks
    half4 Aih[2];
    half8 ApF;
    f32x4 biasA = zero4, biasB = zero4, biasP = zero4;
    float4 xsA[TCH], xsB[TCH];         // wave1 load ping-pong

    if (wid == 0) {
        #pragma unroll
        for (int U = 0; U < 2; ++U) {
            half8 f;
            #pragma unroll
            for (int V = 0; V < 2; ++V)
                #pragma unroll
                for (int i = 0; i < 4; ++i)
                    f[V*4 + i] = (_Float16)(ZSCALE *
                        W_hh[(U*16 + c16)*HID + V*16 + 4*g + i]);
            AhhF[U] = f;
        }
    } else if (wid == 1) {
        #pragma unroll
        for (int U = 0; U < 2; ++U)
            #pragma unroll
            for (int i = 0; i < 4; ++i)
                Aih[U][i] = (_Float16)(ZSCALE *
                    W_ih[(U*16 + c16)*F_IN + 4*g + i]);
        #pragma unroll
        for (int r = 0; r < 4; ++r) {
            const int u = 4*g + r;
            biasA[r] = ZSCALE * (b_ih[u]      + b_hh[u]);
            biasB[r] = ZSCALE * (b_ih[16 + u] + b_hh[16 + u]);
        }
    } else {
        #pragma unroll
        for (int V = 0; V < 2; ++V)
            #pragma unroll
            for (int i = 0; i < 4; ++i)
                ApF[V*4 + i] = (c16 < NCH)
                    ? (_Float16)W_proj[c16*HID + V*16 + 4*g + i]
                    : (_Float16)0.0f;
        #pragma unroll
        for (int r = 0; r < 4; ++r) {
            const int u = 4*g + r;
            biasP[r] = (u < NCH) ? b_proj[u] : 0.0f;  // pad rows -> p=0 (max-safe)
        }
    }

    // wave0 recurrent state: h as the K=32 B fragment (lo16 | hi16)
    half8 Bh = {0,0,0,0,0,0,0,0};
    f32x4 Wc = zero4;                  // wave2 pool window accumulator

    // ---- wave1 helpers ----
    auto w1_load = [&](int c, float4* xs) {
        const int cc = (c < NCHUNK) ? c : NCHUNK - 1;
        #pragma unroll
        for (int m = 0; m < TCH; ++m)
            xs[m] = xsrc[(xrow + cc*TCH + m) * 4 + g];
    };
    auto w1_compute = [&](int buf, const float4* xs) {
        #pragma unroll
        for (int m = 0; m < TCH; ++m) {
            const half4 Bx = pack4(xs[m].x, xs[m].y, xs[m].z, xs[m].w);
            xza_s[buf][m][lane] = u4(mfma16(Aih[0], Bx, biasA));
            xzb_s[buf][m][lane] = u4(mfma16(Aih[1], Bx, biasB));
        }
    };

    // ---- wave0: one chunk of the sequential core (4-deep xz prefetch) ----
    auto w0_chunk = [&](int buf) {
        uint4 ra[4], rb[4];
        #pragma unroll
        for (int i = 0; i < 4; ++i) {
            ra[i] = xza_s[buf][i][lane];
            rb[i] = xzb_s[buf][i][lane];
        }
        #pragma unroll
        for (int tt = 0; tt < TCH; ++tt) {
            const f32x4 xza = f4(ra[tt & 3]);
            const f32x4 xzb = f4(rb[tt & 3]);
            // two independent K=32 MFMAs: za = Ahh(0:15,:)*h + xza, etc.
            const f32x4 za = hmfma32(AhhF[0], Bh, xza);
            const f32x4 zb = hmfma32(AhhF[1], Bh, xzb);
            if (tt + 4 < TCH) {                 // prefetch 4 steps ahead
                ra[tt & 3] = xza_s[buf][tt + 4][lane];
                rb[tt & 3] = xzb_s[buf][tt + 4][lane];
            }
            uint4 hp;
            hp.x = pk2u(act_fast(za[0]), act_fast(za[1]));
            hp.y = pk2u(act_fast(za[2]), act_fast(za[3]));
            hp.z = pk2u(act_fast(zb[0]), act_fast(zb[1]));
            hp.w = pk2u(act_fast(zb[2]), act_fast(zb[3]));
            Bh = __builtin_bit_cast(half8, hp);
            hqs[buf][tt][lane] = hp;
        }
    };

    // ---- wave2: proj + pool for one published chunk ----
    const half8 sl8 = {(_Float16)RRELU_SLOPE, (_Float16)RRELU_SLOPE,
                       (_Float16)RRELU_SLOPE, (_Float16)RRELU_SLOPE,
                       (_Float16)RRELU_SLOPE, (_Float16)RRELU_SLOPE,
                       (_Float16)RRELU_SLOPE, (_Float16)RRELU_SLOPE};
    auto w2_process = [&](int c, int buf) {
        #pragma unroll
        for (int tt = 0; tt < TCH; ++tt) {
            const int t = c*TCH + tt;
            const uint4 hv = hqs[buf][tt][lane];
            const half8 h8 = __builtin_bit_cast(half8, hv);
            const half8 a8 = __builtin_elementwise_max(h8, h8 * sl8); // RReLU
            const f32x4 p  = hmfma32(ApF, a8, biasP);
            const f32x4 q4 = p * p;             // channels 4g+r of batch c16
            if ((tt & 1) == 0) {                // t even (chunk base even)
                const f32x4 pr = Wc + q4;       // closes window t/2 - 1
                if (t >= 2) {
                    const float mloc = fmaxf(fmaxf(pr[0], pr[1]),
                                             fmaxf(pr[2], pr[3]));
                    pbuf[c16*4 + g] = mloc;     // intra-wave, DS FIFO ordered
                    if (g == 0) {
                        const f32x4 pv = *(const f32x4*)&pbuf[c16*4];
                        const float mm = fmaxf(fmaxf(pv[0], pv[1]),
                                               fmaxf(pv[2], pv[3]));
                        outrow[(t >> 1) - 1] = __builtin_amdgcn_sqrtf(mm);
                    }
                }
                Wc = q4;                        // opens window t/2
            } else {
                Wc = Wc + q4;
            }
        }
    };

    // ---- prologue: wave1 fills chunk 0 (buf0) and prefetches chunk 1 ----
    if (wid == 1) {
        w1_load(0, xsA);
        w1_compute(0, xsA);
        w1_load(1, xsA);
    }
    __syncthreads();

    // ---- main loop, unrolled x2 (NCHUNK = 128, even) ----
    for (int cc = 0; cc < NCHUNK; cc += 2) {
        // sub A: chunk cc (buffers 0)
        if (wid == 0) {
            w0_chunk(0);
        } else if (wid == 1) {
            w1_load(cc + 2, xsB);      // issue loads first (latency cover)
            w1_compute(1, xsA);        // xz' for chunk cc+1 -> buf1
        } else {
            if (cc > 0) w2_process(cc - 1, 1);
        }
        __syncthreads();
        // sub B: chunk cc+1 (buffers 1)
        if (wid == 0) {
            w0_chunk(1);
        } else if (wid == 1) {
            w1_load(cc + 3, xsA);
            w1_compute(0, xsB);        // xz' for chunk cc+2 -> buf0
        } else {
            w2_process(cc, 0);
        }
        __syncthreads();
    }
    if (wid == 2) w2_process(NCHUNK - 1, 1);
}

extern "C" void kernel_launch(void* const* d_in, const int* in_sizes, int n_in,
                              void* d_out, int out_size, void* d_ws, size_t ws_size,
                              hipStream_t stream) {
    const float* x      = (const float*)d_in[0];
    const float* W_ih   = (const float*)d_in[1];
    const float* W_hh   = (const float*)d_in[2];
    const float* b_ih   = (const float*)d_in[3];
    const float* b_hh   = (const float*)d_in[4];
    const float* W_proj = (const float*)d_in[5];
    const float* b_proj = (const float*)d_in[6];
    float* out = (float*)d_out;

    dim3 grid(B_ROWS / 16);   // 256 chains; 3 waves (3 SIMDs) per chain
    dim3 block(192);
    hipLaunchKernelGGL(rnn_mfma_kernel, grid, block, 0, stream,
                       x, W_ih, W_hh, b_ih, b_hh, W_proj, b_proj, out);
}